// Round 1
// baseline (552.327 us; speedup 1.0000x reference)
//
#include <hip/hip_runtime.h>

// ---------- helpers ----------
typedef __attribute__((ext_vector_type(8))) short bf16x8;  // 8 bf16 (4 VGPRs)
typedef __attribute__((ext_vector_type(4))) float f32x4;

__device__ __forceinline__ unsigned short f2bf(float f) {
    union { float f; unsigned int u; } v; v.f = f;
    unsigned int u = v.u;
    unsigned int r = (u + 0x7FFFu + ((u >> 16) & 1u)) >> 16;   // RNE
    return (unsigned short)r;
}
__device__ __forceinline__ float bf2f(unsigned short b) {
    union { unsigned int u; float f; } v; v.u = ((unsigned int)b) << 16;
    return v.f;
}

#define GL16(g, l)                                                             \
    __builtin_amdgcn_global_load_lds(                                          \
        (__attribute__((address_space(1))) void*)(void*)(g),                   \
        (__attribute__((address_space(3))) void*)(void*)(l), 16, 0, 0)

// ---------- f32 -> bf16 cast (vectorized, grid-stride) ----------
__global__ void castk(const float* __restrict__ in, unsigned short* __restrict__ out, int n4) {
    int stride = gridDim.x * blockDim.x;
    for (int i = blockIdx.x * blockDim.x + threadIdx.x; i < n4; i += stride) {
        float4 v = ((const float4*)in)[i];
        ushort4 o;
        o.x = f2bf(v.x); o.y = f2bf(v.y); o.z = f2bf(v.z); o.w = f2bf(v.w);
        ((ushort4*)out)[i] = o;
    }
}

// ---------- m97-style NT GEMM: C(MxN) = A(MxK) * B(NxK)^T + bias, opt ReLU ----------
// 128x128 tile, BK=64, 4 waves (2x2), each wave 64x64 = 4x4 mfma_f32_16x16x32_bf16 frags.
#define BM 128
#define BN 128
#define BKK 64

template<int RELU, int OUT_BF16>
__global__ __launch_bounds__(256, 2) void gemm_bt(
    const unsigned short* __restrict__ A,   // M x K  (bf16 bits)
    const unsigned short* __restrict__ Bm,  // N x K  (bf16 bits)
    const float* __restrict__ bias,         // N
    void* __restrict__ Cout,                // M x N  (bf16 or f32)
    int M, int N, int K)
{
    __shared__ __align__(16) unsigned short As[BM * BKK];
    __shared__ __align__(16) unsigned short Bs[BN * BKK];

    const int tid  = threadIdx.x;
    const int lane = tid & 63;
    const int wave = tid >> 6;
    const int wr   = wave >> 1;      // 0..1
    const int wc   = wave & 1;       // 0..1
    const int bm   = blockIdx.y;
    const int bn   = blockIdx.x;

    const long arow0 = (long)bm * BM;
    const long brow0 = (long)bn * BN;

    f32x4 acc[4][4] = {};

    for (int k0 = 0; k0 < K; k0 += BKK) {
        // stage A and B tiles: 128 rows x 64 bf16 = 16KB each; 16B/lane chunks.
        // chunk c = cbase + lane; row = c>>3, colchunk = c&7; LDS byte off = c*16.
        #pragma unroll
        for (int i = 0; i < 4; ++i) {
            int cbase = i * 256 + wave * 64;          // wave-uniform
            int c     = cbase + lane;                 // per-lane
            int row = c >> 3, cc = c & 7;
            const unsigned short* ga = A  + (arow0 + row) * (long)K + k0 + cc * 8;
            const unsigned short* gb = Bm + (brow0 + row) * (long)K + k0 + cc * 8;
            GL16(ga, &As[cbase * 8]);
            GL16(gb, &Bs[cbase * 8]);
        }
        __syncthreads();   // drains vmcnt(0): staged data visible

        #pragma unroll
        for (int kk = 0; kk < 2; ++kk) {
            bf16x8 af[4], bf[4];
            const int g8 = (lane >> 4) * 8;
            const int cl = lane & 15;
            #pragma unroll
            for (int m = 0; m < 4; ++m) {
                int row = wr * 64 + m * 16 + cl;
                af[m] = *(const bf16x8*)&As[row * BKK + kk * 32 + g8];
            }
            #pragma unroll
            for (int n = 0; n < 4; ++n) {
                int row = wc * 64 + n * 16 + cl;
                bf[n] = *(const bf16x8*)&Bs[row * BKK + kk * 32 + g8];
            }
            #pragma unroll
            for (int m = 0; m < 4; ++m)
                #pragma unroll
                for (int n = 0; n < 4; ++n)
                    acc[m][n] = __builtin_amdgcn_mfma_f32_16x16x32_bf16(af[m], bf[n], acc[m][n], 0, 0, 0);
        }
        __syncthreads();   // before next stage overwrites LDS
    }

    // epilogue: C/D layout col=lane&15, row=(lane>>4)*4+reg  [m89]
    const int r4 = (lane >> 4) * 4;
    const int cl = lane & 15;
    float bv[4];
    #pragma unroll
    for (int n = 0; n < 4; ++n) bv[n] = bias[(long)bn * BN + wc * 64 + n * 16 + cl];

    #pragma unroll
    for (int m = 0; m < 4; ++m) {
        long grow = (long)bm * BM + wr * 64 + m * 16 + r4;
        #pragma unroll
        for (int n = 0; n < 4; ++n) {
            long gcol = (long)bn * BN + wc * 64 + n * 16 + cl;
            #pragma unroll
            for (int r = 0; r < 4; ++r) {
                float v = acc[m][n][r] + bv[n];
                if (RELU) v = fmaxf(v, 0.f);
                long idx = (grow + r) * (long)N + gcol;
                if (OUT_BF16) ((unsigned short*)Cout)[idx] = f2bf(v);
                else          ((float*)Cout)[idx]          = v;
            }
        }
    }
}

// ---------- fused: latent(16) -> quantum circuit -> D1 (z @ Wd1^T + bd1, ReLU) ----------
// One wave per batch row. K=1024 latent dots via per-lane partial + butterfly reduce.
__global__ __launch_bounds__(256) void latq_d1(
    const unsigned short* __restrict__ h2,  // B x 1024 bf16
    const float* __restrict__ We3,          // 256 x 1024 (rows 0..15 used)
    const float* __restrict__ be3,          // 256
    const float* __restrict__ P,            // 2 x 16 x 3
    const float* __restrict__ Wd1,          // 1024 x 16
    const float* __restrict__ bd1,          // 1024
    unsigned short* __restrict__ h3)        // B x 1024 bf16
{
    __shared__ float zsh[4][16];
    const int lane = threadIdx.x & 63;
    const int wv   = threadIdx.x >> 6;
    const long row = (long)blockIdx.x * 4 + wv;

    // load this row of h2 into registers (coalesced)
    float hreg[16];
    const unsigned short* hr = h2 + row * 1024;
    #pragma unroll
    for (int j = 0; j < 16; ++j) hreg[j] = bf2f(hr[lane + 64 * j]);

    // 16 latent dot products, butterfly-reduced; lane q keeps latent[q]
    float myth = 0.f;
    #pragma unroll
    for (int q = 0; q < 16; ++q) {
        const float* wq = We3 + q * 1024;
        float p = 0.f;
        #pragma unroll
        for (int j = 0; j < 16; ++j) p += hreg[j] * wq[lane + 64 * j];
        #pragma unroll
        for (int o = 32; o; o >>= 1) p += __shfl_xor(p, o, 64);
        if (lane == q) myth = p + be3[q];
    }

    // per-qubit circuit (exactly the reference complex64 recurrence, in f32)
    if (lane < 16) {
        const int q = lane;
        float ar = cosf(0.5f * myth), ai = 0.f;
        float br = sinf(0.5f * myth), bi = 0.f;
        #pragma unroll
        for (int l = 0; l < 2; ++l) {
            const float* pp = P + (l * 16 + q) * 3;
            float t, c, s, ar2, ai2, br2, bi2;
            // RX: a' = c*a - i s*b ; b' = -i s*a + c*b
            t = 0.5f * pp[0]; c = cosf(t); s = sinf(t);
            ar2 = c * ar + s * bi;  ai2 = c * ai - s * br;
            br2 = c * br + s * ai;  bi2 = c * bi - s * ar;
            ar = ar2; ai = ai2; br = br2; bi = bi2;
            // RY: a' = c*a - s*b ; b' = s*a + c*b
            t = 0.5f * pp[1]; c = cosf(t); s = sinf(t);
            ar2 = c * ar - s * br;  ai2 = c * ai - s * bi;
            br2 = s * ar + c * br;  bi2 = s * ai + c * bi;
            ar = ar2; ai = ai2; br = br2; bi = bi2;
            // RZ: a' = a*e^{-it} ; b' = b*e^{+it}
            t = 0.5f * pp[2]; c = cosf(t); s = sinf(t);
            ar2 = ar * c + ai * s;  ai2 = ai * c - ar * s;
            br2 = br * c - bi * s;  bi2 = bi * c + br * s;
            ar = ar2; ai = ai2; br = br2; bi = bi2;
        }
        zsh[wv][q] = ar * ar + ai * ai - (br * br + bi * bi);
    }
    __syncthreads();

    float z[16];
    #pragma unroll
    for (int q = 0; q < 16; ++q) z[q] = zsh[wv][q];

    // D1: h3[row][j] = relu(sum_q z[q]*Wd1[j][q] + bd1[j])
    unsigned short* orow = h3 + row * 1024;
    #pragma unroll
    for (int i = 0; i < 16; ++i) {
        int j = lane + 64 * i;
        const float4* wrow = (const float4*)(Wd1 + j * 16);
        float acc = bd1[j];
        #pragma unroll
        for (int qq = 0; qq < 4; ++qq) {
            float4 w4 = wrow[qq];
            acc += z[qq * 4 + 0] * w4.x + z[qq * 4 + 1] * w4.y
                 + z[qq * 4 + 2] * w4.z + z[qq * 4 + 3] * w4.w;
        }
        orow[j] = f2bf(fmaxf(acc, 0.f));
    }
}

// ---------- host ----------
static void launch_cast(const float* in, unsigned short* out, long n, hipStream_t stream) {
    int n4 = (int)(n / 4);
    int blocks = (n4 + 255) / 256;
    if (blocks > 2048) blocks = 2048;
    castk<<<blocks, 256, 0, stream>>>(in, out, n4);
}

extern "C" void kernel_launch(void* const* d_in, const int* in_sizes, int n_in,
                              void* d_out, int out_size, void* d_ws, size_t ws_size,
                              hipStream_t stream) {
    const float* x   = (const float*)d_in[0];
    const float* We1 = (const float*)d_in[1];
    const float* be1 = (const float*)d_in[2];
    const float* We2 = (const float*)d_in[3];
    const float* be2 = (const float*)d_in[4];
    const float* We3 = (const float*)d_in[5];
    const float* be3 = (const float*)d_in[6];
    const float* P   = (const float*)d_in[7];
    const float* Wd1 = (const float*)d_in[8];
    const float* bd1 = (const float*)d_in[9];
    const float* Wd2 = (const float*)d_in[10];
    const float* bd2 = (const float*)d_in[11];
    const float* Wd3 = (const float*)d_in[12];
    const float* bd3 = (const float*)d_in[13];

    const int B = 8192, DIN = 4096, NH1 = 2048, NH2 = 1024;

    // workspace layout (stream-ordered aliasing: h4 <- x_bf region, h3 <- h1 region)
    char* w = (char*)d_ws;
    unsigned short* x_bf   = (unsigned short*)(w);                    // 64MB
    unsigned short* h4     = x_bf;                                    // alias (x dead after G1)
    unsigned short* We1_bf = (unsigned short*)(w + 67108864L);        // 16MB
    unsigned short* We2_bf = (unsigned short*)(w + 83886080L);        // 4MB
    unsigned short* Wd2_bf = (unsigned short*)(w + 88080384L);        // 4MB
    unsigned short* Wd3_bf = (unsigned short*)(w + 92274688L);        // 16MB
    unsigned short* h1     = (unsigned short*)(w + 109051904L);       // 32MB
    unsigned short* h3     = h1;                                      // alias (h1 dead after G2)
    unsigned short* h2     = (unsigned short*)(w + 142606336L);       // 16MB
    // total = 159,383,552 bytes

    launch_cast(x,   x_bf,   (long)B * DIN,  stream);
    launch_cast(We1, We1_bf, (long)NH1 * DIN, stream);
    launch_cast(We2, We2_bf, (long)NH2 * NH1, stream);
    launch_cast(Wd2, Wd2_bf, (long)NH1 * NH2, stream);
    launch_cast(Wd3, Wd3_bf, (long)DIN * NH1, stream);

    // G1: h1 = relu(x @ We1^T + be1)            (8192x2048, K=4096)
    gemm_bt<1, 1><<<dim3(NH1 / BN, B / BM), 256, 0, stream>>>(x_bf, We1_bf, be1, h1, B, NH1, DIN);
    // G2: h2 = relu(h1 @ We2^T + be2)           (8192x1024, K=2048)
    gemm_bt<1, 1><<<dim3(NH2 / BN, B / BM), 256, 0, stream>>>(h1, We2_bf, be2, h2, B, NH2, NH1);
    // latent -> quantum -> D1                   (8192x1024)
    latq_d1<<<dim3(B / 4), 256, 0, stream>>>(h2, We3, be3, P, Wd1, bd1, h3);
    // D2: h4 = relu(h3 @ Wd2^T + bd2)           (8192x2048, K=1024)
    gemm_bt<1, 1><<<dim3(NH1 / BN, B / BM), 256, 0, stream>>>(h3, Wd2_bf, bd2, h4, B, NH1, NH2);
    // D3: out = h4 @ Wd3^T + bd3                (8192x4096, K=2048) -> f32
    gemm_bt<0, 0><<<dim3(DIN / BN, B / BM), 256, 0, stream>>>(h4, Wd3_bf, bd3, d_out, B, DIN, NH1);
}

// Round 2
// 451.324 us; speedup vs baseline: 1.2238x; 1.2238x over previous
//
#include <hip/hip_runtime.h>

// ---------- types / helpers ----------
typedef __attribute__((ext_vector_type(8))) short bf16x8;  // 8 bf16 (4 VGPRs)
typedef __attribute__((ext_vector_type(4))) float f32x4;

__device__ __forceinline__ unsigned short f2bf(float f) {
    union { float f; unsigned int u; } v; v.f = f;
    unsigned int u = v.u;
    unsigned int r = (u + 0x7FFFu + ((u >> 16) & 1u)) >> 16;   // RNE
    return (unsigned short)r;
}
__device__ __forceinline__ float bf2f(unsigned short b) {
    union { unsigned int u; float f; } v; v.u = ((unsigned int)b) << 16;
    return v.f;
}

#define GL16(g, l)                                                             \
    __builtin_amdgcn_global_load_lds(                                          \
        (__attribute__((address_space(1))) void*)(void*)(g),                   \
        (__attribute__((address_space(3))) void*)(void*)(l), 16, 0, 0)

#define SBAR() __builtin_amdgcn_sched_barrier(0)
#define BAR()  do { SBAR(); __builtin_amdgcn_s_barrier(); SBAR(); } while (0)

// ---------- f32 -> bf16 cast ----------
__global__ void castk(const float* __restrict__ in, unsigned short* __restrict__ out, int n4) {
    int stride = gridDim.x * blockDim.x;
    for (int i = blockIdx.x * blockDim.x + threadIdx.x; i < n4; i += stride) {
        float4 v = ((const float4*)in)[i];
        ushort4 o;
        o.x = f2bf(v.x); o.y = f2bf(v.y); o.z = f2bf(v.z); o.w = f2bf(v.w);
        ((ushort4*)out)[i] = o;
    }
}

// ---------- 8-phase 256x256 NT GEMM: C = A(MxK) * B(NxK)^T + bias ----------
// 512 thr = 8 waves (2M x 4N). Per-wave 128x64 output as 2x2 quadrants x (4x2 frags).
// LDS 128KB: A/B x dbuf x half(128 rows x 64 cols bf16 = 16KB).
// Wave row-mapping interleaved across halves: quadrant mh/nh selects LDS half.
// Phase order per K-tile: Q00(read A0,B0), Q01(read B1), Q11(read A1), Q10(reuse).
// Staging per phase: P1->(t+1).A1, P2->(t+2).B0, P3->(t+2).A0, P4->(t+2).B1 + vmcnt(6).
// Swizzle (T2): logical byte-col c2 stored at c2 ^ ((row&7)<<4); gload_lds dest linear,
// source pre-swizzled (rule #21). NT must be even and >= 2 (true for all shapes here).

template<int RELU, int OUT_BF16>
__global__ __launch_bounds__(512, 2) void gemm8p(
    const unsigned short* __restrict__ A,   // M x K bf16
    const unsigned short* __restrict__ Bm,  // N x K bf16
    const float* __restrict__ bias,         // N
    void* __restrict__ Cout,                // M x N
    int N, int K, int NT)
{
    __shared__ __align__(16) unsigned short lds[65536];   // 128 KiB

    const int tid  = threadIdx.x;
    const int lane = tid & 63;
    const int w    = tid >> 6;
    const int wm   = w >> 2;           // 0..1
    const int wn   = w & 3;            // 0..3
    const int bm   = blockIdx.y;
    const int bn   = blockIdx.x;

    const long arow0 = (long)bm * 256;
    const long brow0 = (long)bn * 256;

    // ---- staging constants (per thread): 2 chunks of 16B per half-tile stage ----
    const int  sc0 = tid,        sc1 = 512 + tid;
    const int  sr0 = sc0 >> 3,   sr1 = sc1 >> 3;                       // row in half
    const int  so0 = (((sc0 & 7) * 16) ^ ((sr0 & 7) << 4)) >> 1;      // logical col (ushort)
    const int  so1 = (((sc1 & 7) * 16) ^ ((sr1 & 7) << 4)) >> 1;
    const long soff0 = (long)sr0 * K + so0;
    const long soff1 = (long)sr1 * K + so1;
    const int  lb0 = (w * 64) * 8;            // wave-uniform LDS chunk base (ushort idx)
    const int  lb1 = (512 + w * 64) * 8;

    // ---- read-side constants ----
    const int cl  = lane & 15;
    const int g16 = (lane >> 4) * 16;                 // byte col of this lane's 16B chunk
    const int sw  = (cl & 7) << 4;
    const int cK0 = (g16 ^ sw) >> 1;                  // kk=0 swizzled col (ushort)
    const int cK1 = ((64 + g16) ^ sw) >> 1;           // kk=1
    const int arb = wm * 64 + cl;                     // A row base within half
    const int brb = wn * 32 + cl;                     // B row base within half

    f32x4  acc[2][2][4][2] = {};
    bf16x8 ar[4][2], b0r[2][2], b1r[2][2];

#define STAGE(G, growbase, t2, h, lo) do {                                     \
        int b_  = (t2) & 1;                                                    \
        int tt_ = (t2) >= NT ? (t2) - NT : (t2);                               \
        const unsigned short* gb_ = (G) + ((growbase) + (long)(h) * 128) * (long)K + (long)tt_ * 64; \
        unsigned short* lh_ = &lds[(lo) + (b_ * 2 + (h)) * 8192];              \
        GL16(gb_ + soff0, lh_ + lb0);                                          \
        GL16(gb_ + soff1, lh_ + lb1);                                          \
    } while (0)
#define STAGE_A(t2, h) STAGE(A,  arow0, t2, h, 0)
#define STAGE_B(t2, h) STAGE(Bm, brow0, t2, h, 32768)

#define READA(AR, mh, b_) do {                                                 \
        const unsigned short* ab_ = &lds[((b_) * 2 + (mh)) * 8192];            \
        _Pragma("unroll") for (int mp_ = 0; mp_ < 4; ++mp_) {                  \
            const unsigned short* rp_ = ab_ + (arb + mp_ * 16) * 64;           \
            AR[mp_][0] = *(const bf16x8*)(rp_ + cK0);                          \
            AR[mp_][1] = *(const bf16x8*)(rp_ + cK1);                          \
        }                                                                      \
    } while (0)
#define READB(BR, nh, b_) do {                                                 \
        const unsigned short* bb_ = &lds[32768 + ((b_) * 2 + (nh)) * 8192];    \
        _Pragma("unroll") for (int np_ = 0; np_ < 2; ++np_) {                  \
            const unsigned short* rp_ = bb_ + (brb + np_ * 16) * 64;           \
            BR[np_][0] = *(const bf16x8*)(rp_ + cK0);                          \
            BR[np_][1] = *(const bf16x8*)(rp_ + cK1);                          \
        }                                                                      \
    } while (0)
#define QUAD(mh, nh, AR, BR) do {                                              \
        __builtin_amdgcn_s_setprio(1);                                         \
        _Pragma("unroll") for (int mp_ = 0; mp_ < 4; ++mp_)                    \
        _Pragma("unroll") for (int np_ = 0; np_ < 2; ++np_)                    \
        _Pragma("unroll") for (int kk_ = 0; kk_ < 2; ++kk_)                    \
            acc[mh][nh][mp_][np_] = __builtin_amdgcn_mfma_f32_16x16x32_bf16(   \
                AR[mp_][kk_], BR[np_][kk_], acc[mh][nh][mp_][np_], 0, 0, 0);   \
        __builtin_amdgcn_s_setprio(0);                                         \
    } while (0)
#define VM6() do { SBAR(); asm volatile("s_waitcnt vmcnt(6)" ::: "memory"); SBAR(); } while (0)

    // ---- prologue: stage tile0 fully + tile1 {B0,A0,B1}; wait first 4 halves ----
    STAGE_B(0, 0); STAGE_A(0, 0); STAGE_B(0, 1); STAGE_A(0, 1);
    STAGE_B(1, 0); STAGE_A(1, 0); STAGE_B(1, 1);
    VM6();
    BAR();

    for (int t = 0; t < NT; ++t) {
        const int b = t & 1;
        // P1: Q(0,0)
        READA(ar, 0, b);
        READB(b0r, 0, b);
        STAGE_A(t + 1, 1);
        BAR();
        QUAD(0, 0, ar, b0r);
        BAR();
        // P2: Q(0,1)
        READB(b1r, 1, b);
        STAGE_B(t + 2, 0);
        BAR();
        QUAD(0, 1, ar, b1r);
        BAR();
        // P3: Q(1,1)
        READA(ar, 1, b);
        STAGE_A(t + 2, 0);
        BAR();
        QUAD(1, 1, ar, b1r);
        BAR();
        // P4: Q(1,0)
        STAGE_B(t + 2, 1);
        VM6();
        BAR();
        QUAD(1, 0, ar, b0r);
        BAR();
    }

    // drain dummy wrap-stagings before epilogue / kernel end
    SBAR(); asm volatile("s_waitcnt vmcnt(0)" ::: "memory"); SBAR();

    // ---- epilogue: C/D layout col=lane&15, row=(lane>>4)*4+reg ----
    const int r4 = (lane >> 4) * 4;
    float bv[2][2];
    #pragma unroll
    for (int nh = 0; nh < 2; ++nh)
        #pragma unroll
        for (int np = 0; np < 2; ++np)
            bv[nh][np] = bias[(long)bn * 256 + nh * 128 + wn * 32 + np * 16 + cl];

    #pragma unroll
    for (int mh = 0; mh < 2; ++mh)
        #pragma unroll
        for (int mp = 0; mp < 4; ++mp) {
            long grow = (long)bm * 256 + mh * 128 + wm * 64 + mp * 16 + r4;
            #pragma unroll
            for (int nh = 0; nh < 2; ++nh)
                #pragma unroll
                for (int np = 0; np < 2; ++np) {
                    long gcol = (long)bn * 256 + nh * 128 + wn * 32 + np * 16 + cl;
                    #pragma unroll
                    for (int r = 0; r < 4; ++r) {
                        float v = acc[mh][nh][mp][np][r] + bv[nh][np];
                        if (RELU) v = fmaxf(v, 0.f);
                        long idx = (grow + r) * (long)N + gcol;
                        if (OUT_BF16) ((unsigned short*)Cout)[idx] = f2bf(v);
                        else          ((float*)Cout)[idx]          = v;
                    }
                }
        }
#undef STAGE
#undef STAGE_A
#undef STAGE_B
#undef READA
#undef READB
#undef QUAD
#undef VM6
}

// ---------- fused: latent(16) -> quantum circuit -> D1 ----------
__global__ __launch_bounds__(256) void latq_d1(
    const unsigned short* __restrict__ h2,  // B x 1024 bf16
    const float* __restrict__ We3,          // 256 x 1024 (rows 0..15 used)
    const float* __restrict__ be3,          // 256
    const float* __restrict__ P,            // 2 x 16 x 3
    const float* __restrict__ Wd1,          // 1024 x 16
    const float* __restrict__ bd1,          // 1024
    unsigned short* __restrict__ h3)        // B x 1024 bf16
{
    __shared__ float zsh[4][16];
    const int lane = threadIdx.x & 63;
    const int wv   = threadIdx.x >> 6;
    const long row = (long)blockIdx.x * 4 + wv;

    float hreg[16];
    const unsigned short* hr = h2 + row * 1024;
    #pragma unroll
    for (int j = 0; j < 16; ++j) hreg[j] = bf2f(hr[lane + 64 * j]);

    float myth = 0.f;
    #pragma unroll
    for (int q = 0; q < 16; ++q) {
        const float* wq = We3 + q * 1024;
        float p = 0.f;
        #pragma unroll
        for (int j = 0; j < 16; ++j) p += hreg[j] * wq[lane + 64 * j];
        #pragma unroll
        for (int o = 32; o; o >>= 1) p += __shfl_xor(p, o, 64);
        if (lane == q) myth = p + be3[q];
    }

    if (lane < 16) {
        const int q = lane;
        float ar = cosf(0.5f * myth), ai = 0.f;
        float br = sinf(0.5f * myth), bi = 0.f;
        #pragma unroll
        for (int l = 0; l < 2; ++l) {
            const float* pp = P + (l * 16 + q) * 3;
            float t, c, s, ar2, ai2, br2, bi2;
            t = 0.5f * pp[0]; c = cosf(t); s = sinf(t);
            ar2 = c * ar + s * bi;  ai2 = c * ai - s * br;
            br2 = c * br + s * ai;  bi2 = c * bi - s * ar;
            ar = ar2; ai = ai2; br = br2; bi = bi2;
            t = 0.5f * pp[1]; c = cosf(t); s = sinf(t);
            ar2 = c * ar - s * br;  ai2 = c * ai - s * bi;
            br2 = s * ar + c * br;  bi2 = s * ai + c * bi;
            ar = ar2; ai = ai2; br = br2; bi = bi2;
            t = 0.5f * pp[2]; c = cosf(t); s = sinf(t);
            ar2 = ar * c + ai * s;  ai2 = ai * c - ar * s;
            br2 = br * c - bi * s;  bi2 = bi * c + br * s;
            ar = ar2; ai = ai2; br = br2; bi = bi2;
        }
        zsh[wv][q] = ar * ar + ai * ai - (br * br + bi * bi);
    }
    __syncthreads();

    float z[16];
    #pragma unroll
    for (int q = 0; q < 16; ++q) z[q] = zsh[wv][q];

    unsigned short* orow = h3 + row * 1024;
    #pragma unroll
    for (int i = 0; i < 16; ++i) {
        int j = lane + 64 * i;
        const float4* wrow = (const float4*)(Wd1 + j * 16);
        float acc = bd1[j];
        #pragma unroll
        for (int qq = 0; qq < 4; ++qq) {
            float4 w4 = wrow[qq];
            acc += z[qq * 4 + 0] * w4.x + z[qq * 4 + 1] * w4.y
                 + z[qq * 4 + 2] * w4.z + z[qq * 4 + 3] * w4.w;
        }
        orow[j] = f2bf(fmaxf(acc, 0.f));
    }
}

// ---------- host ----------
static void launch_cast(const float* in, unsigned short* out, long n, hipStream_t stream) {
    int n4 = (int)(n / 4);
    int blocks = (n4 + 255) / 256;
    if (blocks > 2048) blocks = 2048;
    castk<<<blocks, 256, 0, stream>>>(in, out, n4);
}

extern "C" void kernel_launch(void* const* d_in, const int* in_sizes, int n_in,
                              void* d_out, int out_size, void* d_ws, size_t ws_size,
                              hipStream_t stream) {
    const float* x   = (const float*)d_in[0];
    const float* We1 = (const float*)d_in[1];
    const float* be1 = (const float*)d_in[2];
    const float* We2 = (const float*)d_in[3];
    const float* be2 = (const float*)d_in[4];
    const float* We3 = (const float*)d_in[5];
    const float* be3 = (const float*)d_in[6];
    const float* P   = (const float*)d_in[7];
    const float* Wd1 = (const float*)d_in[8];
    const float* bd1 = (const float*)d_in[9];
    const float* Wd2 = (const float*)d_in[10];
    const float* bd2 = (const float*)d_in[11];
    const float* Wd3 = (const float*)d_in[12];
    const float* bd3 = (const float*)d_in[13];

    const int B = 8192, DIN = 4096, NH1 = 2048, NH2 = 1024;

    char* w = (char*)d_ws;
    unsigned short* x_bf   = (unsigned short*)(w);                    // 64MB
    unsigned short* h4     = x_bf;                                    // alias (x dead after G1)
    unsigned short* We1_bf = (unsigned short*)(w + 67108864L);        // 16MB
    unsigned short* We2_bf = (unsigned short*)(w + 83886080L);        // 4MB
    unsigned short* Wd2_bf = (unsigned short*)(w + 88080384L);        // 4MB
    unsigned short* Wd3_bf = (unsigned short*)(w + 92274688L);        // 16MB
    unsigned short* h1     = (unsigned short*)(w + 109051904L);       // 32MB
    unsigned short* h3     = h1;                                      // alias (h1 dead after G2)
    unsigned short* h2     = (unsigned short*)(w + 142606336L);       // 16MB

    launch_cast(x,   x_bf,   (long)B * DIN,   stream);
    launch_cast(We1, We1_bf, (long)NH1 * DIN, stream);
    launch_cast(We2, We2_bf, (long)NH2 * NH1, stream);
    launch_cast(Wd2, Wd2_bf, (long)NH1 * NH2, stream);
    launch_cast(Wd3, Wd3_bf, (long)DIN * NH1, stream);

    // G1: h1 = relu(x @ We1^T + be1)   8192x2048 K=4096
    gemm8p<1, 1><<<dim3(NH1 / 256, B / 256), 512, 0, stream>>>(x_bf, We1_bf, be1, h1, NH1, DIN, DIN >> 6);
    // G2: h2 = relu(h1 @ We2^T + be2)  8192x1024 K=2048
    gemm8p<1, 1><<<dim3(NH2 / 256, B / 256), 512, 0, stream>>>(h1, We2_bf, be2, h2, NH2, NH1, NH1 >> 6);
    // latent -> quantum -> D1
    latq_d1<<<dim3(B / 4), 256, 0, stream>>>(h2, We3, be3, P, Wd1, bd1, h3);
    // D2: h4 = relu(h3 @ Wd2^T + bd2)  8192x2048 K=1024
    gemm8p<1, 1><<<dim3(NH1 / 256, B / 256), 512, 0, stream>>>(h3, Wd2_bf, bd2, h4, NH1, NH2, NH2 >> 6);
    // D3: out = h4 @ Wd3^T + bd3       8192x4096 K=2048 -> f32
    gemm8p<0, 0><<<dim3(DIN / 256, B / 256), 512, 0, stream>>>(h4, Wd3_bf, bd3, d_out, DIN, NH1, NH1 >> 6);
}

// Round 3
// 441.753 us; speedup vs baseline: 1.2503x; 1.0217x over previous
//
#include <hip/hip_runtime.h>

// ---------- types / helpers ----------
typedef __attribute__((ext_vector_type(8))) short bf16x8;  // 8 bf16 (4 VGPRs)
typedef __attribute__((ext_vector_type(4))) float f32x4;

__device__ __forceinline__ unsigned short f2bf(float f) {
    union { float f; unsigned int u; } v; v.f = f;
    unsigned int u = v.u;
    unsigned int r = (u + 0x7FFFu + ((u >> 16) & 1u)) >> 16;   // RNE
    return (unsigned short)r;
}
__device__ __forceinline__ float bf2f(unsigned short b) {
    union { unsigned int u; float f; } v; v.u = ((unsigned int)b) << 16;
    return v.f;
}

#define GL16(g, l)                                                             \
    __builtin_amdgcn_global_load_lds(                                          \
        (__attribute__((address_space(1))) void*)(void*)(g),                   \
        (__attribute__((address_space(3))) void*)(void*)(l), 16, 0, 0)

#define SBAR() __builtin_amdgcn_sched_barrier(0)
#define BAR()  do { SBAR(); __builtin_amdgcn_s_barrier(); SBAR(); } while (0)

// ---------- f32 -> bf16 cast ----------
__global__ void castk(const float* __restrict__ in, unsigned short* __restrict__ out, int n4) {
    int stride = gridDim.x * blockDim.x;
    for (int i = blockIdx.x * blockDim.x + threadIdx.x; i < n4; i += stride) {
        float4 v = ((const float4*)in)[i];
        ushort4 o;
        o.x = f2bf(v.x); o.y = f2bf(v.y); o.z = f2bf(v.z); o.w = f2bf(v.w);
        ((ushort4*)out)[i] = o;
    }
}

// ---------- 8-phase 256x256 NT GEMM, pipelined register loads ----------
// 512 thr = 8 waves (2M x 4N). Per-wave 128x64 output as 2x2 quadrants x (4x2 frags).
// LDS 128KB: {A,B} x dbuf x half(128 rows x 64 cols bf16 = 16KB).
// Quadrant order per K-tile: Q00(a0,b0) Q01(a0,b1) Q11(a1,b1) Q10(a1,b0).
// ds_reads one phase ahead of consumption (8/4/8/4 per phase):
//   P1: read a1(t);          stage (t+1).A1
//   P2: read b1(t);          stage (t+2).B0; vmcnt(6)  [lands (t+1).B0,A0]
//   P3: read a0(t+1);        stage (t+2).A0
//   P4: [QUAD] read b0(t+1); stage (t+2).B1; vmcnt(6)  [lands (t+1).B1,A1]
// Every vmcnt is >=1 barrier before the dependent cross-wave LDS read.

template<int RELU, int OUT_BF16>
__global__ __launch_bounds__(512, 2) void gemm8p(
    const unsigned short* __restrict__ A,   // M x K bf16
    const unsigned short* __restrict__ Bm,  // N x K bf16
    const float* __restrict__ bias,         // N
    void* __restrict__ Cout,                // M x N
    int N, int K, int NT)
{
    __shared__ __align__(16) unsigned short lds[65536];   // 128 KiB

    const int tid  = threadIdx.x;
    const int lane = tid & 63;
    const int w    = tid >> 6;
    const int wm   = w >> 2;           // 0..1
    const int wn   = w & 3;            // 0..3
    const int bm   = blockIdx.y;
    const int bn   = blockIdx.x;

    const long arow0 = (long)bm * 256;
    const long brow0 = (long)bn * 256;

    // ---- staging constants: 2 chunks of 16B per half-tile stage ----
    const int sc0 = tid,      sc1 = 512 + tid;
    const int sr0 = sc0 >> 3, sr1 = sc1 >> 3;                      // row in half
    const int so0 = (((sc0 & 7) * 16) ^ ((sr0 & 7) << 4)) >> 1;    // swizzled col (ushort)
    const int so1 = (((sc1 & 7) * 16) ^ ((sr1 & 7) << 4)) >> 1;
    const int soff0 = sr0 * K + so0;                               // fits int (<2^23)
    const int soff1 = sr1 * K + so1;
    const int lb0 = (w * 64) * 8;          // wave-uniform LDS chunk base (ushort idx)
    const int lb1 = (512 + w * 64) * 8;

    // ---- read-side constants ----
    const int cl  = lane & 15;
    const int g16 = (lane >> 4) * 16;                 // byte col of lane's 16B chunk
    const int sw  = (cl & 7) << 4;
    const int cK0 = (g16 ^ sw) >> 1;                  // kk=0 swizzled col (ushort)
    const int cK1 = ((64 + g16) ^ sw) >> 1;           // kk=1
    const int arb = wm * 64 + cl;                     // A row base within half
    const int brb = wn * 32 + cl;                     // B row base within half

    f32x4  acc[2][2][4][2] = {};
    bf16x8 a0[4][2], a1[4][2], b0[2][2], b1[2][2];

#define STAGE(G, growbase, t2, h, lo) do {                                     \
        int b_  = (t2) & 1;                                                    \
        int tt_ = (t2) >= NT ? (t2) - NT : (t2);                               \
        const unsigned short* gb_ = (G) + ((growbase) + (long)(h) * 128) * (long)K + (long)tt_ * 64; \
        unsigned short* lh_ = &lds[(lo) + (b_ * 2 + (h)) * 8192];              \
        GL16(gb_ + soff0, lh_ + lb0);                                          \
        GL16(gb_ + soff1, lh_ + lb1);                                          \
    } while (0)
#define STAGE_A(t2, h) STAGE(A,  arow0, t2, h, 0)
#define STAGE_B(t2, h) STAGE(Bm, brow0, t2, h, 32768)

#define READA(AR, mh, b_) do {                                                 \
        const unsigned short* ab_ = &lds[((b_) * 2 + (mh)) * 8192];            \
        _Pragma("unroll") for (int mp_ = 0; mp_ < 4; ++mp_) {                  \
            const unsigned short* rp_ = ab_ + (arb + mp_ * 16) * 64;           \
            AR[mp_][0] = *(const bf16x8*)(rp_ + cK0);                          \
            AR[mp_][1] = *(const bf16x8*)(rp_ + cK1);                          \
        }                                                                      \
    } while (0)
#define READB(BR, nh, b_) do {                                                 \
        const unsigned short* bb_ = &lds[32768 + ((b_) * 2 + (nh)) * 8192];    \
        _Pragma("unroll") for (int np_ = 0; np_ < 2; ++np_) {                  \
            const unsigned short* rp_ = bb_ + (brb + np_ * 16) * 64;           \
            BR[np_][0] = *(const bf16x8*)(rp_ + cK0);                          \
            BR[np_][1] = *(const bf16x8*)(rp_ + cK1);                          \
        }                                                                      \
    } while (0)
#define QUAD(mh, nh, AR, BR) do {                                              \
        __builtin_amdgcn_s_setprio(1);                                         \
        _Pragma("unroll") for (int mp_ = 0; mp_ < 4; ++mp_)                    \
        _Pragma("unroll") for (int np_ = 0; np_ < 2; ++np_)                    \
        _Pragma("unroll") for (int kk_ = 0; kk_ < 2; ++kk_)                    \
            acc[mh][nh][mp_][np_] = __builtin_amdgcn_mfma_f32_16x16x32_bf16(   \
                AR[mp_][kk_], BR[np_][kk_], acc[mh][nh][mp_][np_], 0, 0, 0);   \
        __builtin_amdgcn_s_setprio(0);                                         \
    } while (0)
#define VM6() do { SBAR(); asm volatile("s_waitcnt vmcnt(6)" ::: "memory"); SBAR(); } while (0)

    // ---- prologue: stage tile0 fully + tile1 {B0,A0,B1}; land tile0; preload a0,b0 ----
    STAGE_B(0, 0); STAGE_A(0, 0); STAGE_B(0, 1); STAGE_A(0, 1);
    STAGE_B(1, 0); STAGE_A(1, 0); STAGE_B(1, 1);
    VM6();
    BAR();
    READA(a0, 0, 0);
    READB(b0, 0, 0);

    for (int t = 0; t < NT; ++t) {
        const int b = t & 1;
        // P1
        READA(a1, 1, b);
        STAGE_A(t + 1, 1);
        BAR();
        QUAD(0, 0, a0, b0);
        BAR();
        // P2
        READB(b1, 1, b);
        STAGE_B(t + 2, 0);
        VM6();
        BAR();
        QUAD(0, 1, a0, b1);
        BAR();
        // P3
        READA(a0, 0, b ^ 1);
        STAGE_A(t + 2, 0);
        BAR();
        QUAD(1, 1, a1, b1);
        BAR();
        // P4
        STAGE_B(t + 2, 1);
        VM6();
        BAR();
        QUAD(1, 0, a1, b0);
        READB(b0, 0, b ^ 1);
        BAR();
    }

    // drain wrap stagings before LDS reuse / kernel end
    SBAR(); asm volatile("s_waitcnt vmcnt(0)" ::: "memory"); SBAR();
    BAR();

    // ---- epilogue ----
    const int r4 = (lane >> 4) * 4;
    float bv[2][2];
    #pragma unroll
    for (int nh = 0; nh < 2; ++nh)
        #pragma unroll
        for (int np = 0; np < 2; ++np)
            bv[nh][np] = bias[(long)bn * 256 + nh * 128 + wn * 32 + np * 16 + cl];

    if (OUT_BF16) {
        // LDS-bounce for coalesced bf16 stores (fixes 4x write amplification)
        unsigned short* epi = lds;
        #pragma unroll
        for (int h = 0; h < 2; ++h) {
            if (h) BAR();
            #pragma unroll
            for (int mp = 0; mp < 4; ++mp)
                #pragma unroll
                for (int nh = 0; nh < 2; ++nh)
                    #pragma unroll
                    for (int np = 0; np < 2; ++np)
                        #pragma unroll
                        for (int r = 0; r < 4; ++r) {
                            float v = acc[h][nh][mp][np][r] + bv[nh][np];
                            if (RELU) v = fmaxf(v, 0.f);
                            int lrow = wm * 64 + mp * 16 + r4 + r;
                            int lcol = nh * 128 + wn * 32 + np * 16 + cl;
                            epi[lrow * 264 + lcol] = f2bf(v);
                        }
            BAR();
            long rowg0 = (long)bm * 256 + h * 128;
            #pragma unroll
            for (int i = 0; i < 8; ++i) {
                int row = (tid >> 5) + i * 16;
                int cc  = (tid & 31) * 8;
                bf16x8 v8 = *(const bf16x8*)&epi[row * 264 + cc];
                *(bf16x8*)((unsigned short*)Cout + (rowg0 + row) * (long)N + (long)bn * 256 + cc) = v8;
            }
        }
    } else {
        // direct f32 stores (64B/row-group, no amplification)
        #pragma unroll
        for (int mh = 0; mh < 2; ++mh)
            #pragma unroll
            for (int mp = 0; mp < 4; ++mp) {
                long grow = (long)bm * 256 + mh * 128 + wm * 64 + mp * 16 + r4;
                #pragma unroll
                for (int nh = 0; nh < 2; ++nh)
                    #pragma unroll
                    for (int np = 0; np < 2; ++np) {
                        long gcol = (long)bn * 256 + nh * 128 + wn * 32 + np * 16 + cl;
                        #pragma unroll
                        for (int r = 0; r < 4; ++r) {
                            float v = acc[mh][nh][mp][np][r] + bv[nh][np];
                            if (RELU) v = fmaxf(v, 0.f);
                            ((float*)Cout)[(grow + r) * (long)N + gcol] = v;
                        }
                    }
            }
    }
#undef STAGE
#undef STAGE_A
#undef STAGE_B
#undef READA
#undef READB
#undef QUAD
#undef VM6
}

// ---------- fused: latent(16) -> quantum circuit -> D1 ----------
__global__ __launch_bounds__(256) void latq_d1(
    const unsigned short* __restrict__ h2,  // B x 1024 bf16
    const float* __restrict__ We3,          // 256 x 1024 (rows 0..15 used)
    const float* __restrict__ be3,          // 256
    const float* __restrict__ P,            // 2 x 16 x 3
    const float* __restrict__ Wd1,          // 1024 x 16
    const float* __restrict__ bd1,          // 1024
    unsigned short* __restrict__ h3)        // B x 1024 bf16
{
    __shared__ float zsh[4][16];
    const int lane = threadIdx.x & 63;
    const int wv   = threadIdx.x >> 6;
    const long row = (long)blockIdx.x * 4 + wv;

    float hreg[16];
    const unsigned short* hr = h2 + row * 1024;
    #pragma unroll
    for (int j = 0; j < 16; ++j) hreg[j] = bf2f(hr[lane + 64 * j]);

    float myth = 0.f;
    #pragma unroll
    for (int q = 0; q < 16; ++q) {
        const float* wq = We3 + q * 1024;
        float p = 0.f;
        #pragma unroll
        for (int j = 0; j < 16; ++j) p += hreg[j] * wq[lane + 64 * j];
        #pragma unroll
        for (int o = 32; o; o >>= 1) p += __shfl_xor(p, o, 64);
        if (lane == q) myth = p + be3[q];
    }

    if (lane < 16) {
        const int q = lane;
        float ar = cosf(0.5f * myth), ai = 0.f;
        float br = sinf(0.5f * myth), bi = 0.f;
        #pragma unroll
        for (int l = 0; l < 2; ++l) {
            const float* pp = P + (l * 16 + q) * 3;
            float t, c, s, ar2, ai2, br2, bi2;
            t = 0.5f * pp[0]; c = cosf(t); s = sinf(t);
            ar2 = c * ar + s * bi;  ai2 = c * ai - s * br;
            br2 = c * br + s * ai;  bi2 = c * bi - s * ar;
            ar = ar2; ai = ai2; br = br2; bi = bi2;
            t = 0.5f * pp[1]; c = cosf(t); s = sinf(t);
            ar2 = c * ar - s * br;  ai2 = c * ai - s * bi;
            br2 = s * ar + c * br;  bi2 = s * ai + c * bi;
            ar = ar2; ai = ai2; br = br2; bi = bi2;
            t = 0.5f * pp[2]; c = cosf(t); s = sinf(t);
            ar2 = ar * c + ai * s;  ai2 = ai * c - ar * s;
            br2 = br * c - bi * s;  bi2 = bi * c + br * s;
            ar = ar2; ai = ai2; br = br2; bi = bi2;
        }
        zsh[wv][q] = ar * ar + ai * ai - (br * br + bi * bi);
    }
    __syncthreads();

    float z[16];
    #pragma unroll
    for (int q = 0; q < 16; ++q) z[q] = zsh[wv][q];

    unsigned short* orow = h3 + row * 1024;
    #pragma unroll
    for (int i = 0; i < 16; ++i) {
        int j = lane + 64 * i;
        const float4* wrow = (const float4*)(Wd1 + j * 16);
        float acc = bd1[j];
        #pragma unroll
        for (int qq = 0; qq < 4; ++qq) {
            float4 w4 = wrow[qq];
            acc += z[qq * 4 + 0] * w4.x + z[qq * 4 + 1] * w4.y
                 + z[qq * 4 + 2] * w4.z + z[qq * 4 + 3] * w4.w;
        }
        orow[j] = f2bf(fmaxf(acc, 0.f));
    }
}

// ---------- host ----------
static void launch_cast(const float* in, unsigned short* out, long n, hipStream_t stream) {
    int n4 = (int)(n / 4);
    int blocks = (n4 + 255) / 256;
    if (blocks > 2048) blocks = 2048;
    castk<<<blocks, 256, 0, stream>>>(in, out, n4);
}

extern "C" void kernel_launch(void* const* d_in, const int* in_sizes, int n_in,
                              void* d_out, int out_size, void* d_ws, size_t ws_size,
                              hipStream_t stream) {
    const float* x   = (const float*)d_in[0];
    const float* We1 = (const float*)d_in[1];
    const float* be1 = (const float*)d_in[2];
    const float* We2 = (const float*)d_in[3];
    const float* be2 = (const float*)d_in[4];
    const float* We3 = (const float*)d_in[5];
    const float* be3 = (const float*)d_in[6];
    const float* P   = (const float*)d_in[7];
    const float* Wd1 = (const float*)d_in[8];
    const float* bd1 = (const float*)d_in[9];
    const float* Wd2 = (const float*)d_in[10];
    const float* bd2 = (const float*)d_in[11];
    const float* Wd3 = (const float*)d_in[12];
    const float* bd3 = (const float*)d_in[13];

    const int B = 8192, DIN = 4096, NH1 = 2048, NH2 = 1024;

    char* w = (char*)d_ws;
    unsigned short* x_bf   = (unsigned short*)(w);                    // 64MB
    unsigned short* h4     = x_bf;                                    // alias (x dead after G1)
    unsigned short* We1_bf = (unsigned short*)(w + 67108864L);        // 16MB
    unsigned short* We2_bf = (unsigned short*)(w + 83886080L);        // 4MB
    unsigned short* Wd2_bf = (unsigned short*)(w + 88080384L);        // 4MB
    unsigned short* Wd3_bf = (unsigned short*)(w + 92274688L);        // 16MB
    unsigned short* h1     = (unsigned short*)(w + 109051904L);       // 32MB
    unsigned short* h3     = h1;                                      // alias (h1 dead after G2)
    unsigned short* h2     = (unsigned short*)(w + 142606336L);       // 16MB

    launch_cast(x,   x_bf,   (long)B * DIN,   stream);
    launch_cast(We1, We1_bf, (long)NH1 * DIN, stream);
    launch_cast(We2, We2_bf, (long)NH2 * NH1, stream);
    launch_cast(Wd2, Wd2_bf, (long)NH1 * NH2, stream);
    launch_cast(Wd3, Wd3_bf, (long)DIN * NH1, stream);

    // G1: h1 = relu(x @ We1^T + be1)   8192x2048 K=4096
    gemm8p<1, 1><<<dim3(NH1 / 256, B / 256), 512, 0, stream>>>(x_bf, We1_bf, be1, h1, NH1, DIN, DIN >> 6);
    // G2: h2 = relu(h1 @ We2^T + be2)  8192x1024 K=2048
    gemm8p<1, 1><<<dim3(NH2 / 256, B / 256), 512, 0, stream>>>(h1, We2_bf, be2, h2, NH2, NH1, NH1 >> 6);
    // latent -> quantum -> D1
    latq_d1<<<dim3(B / 4), 256, 0, stream>>>(h2, We3, be3, P, Wd1, bd1, h3);
    // D2: h4 = relu(h3 @ Wd2^T + bd2)  8192x2048 K=1024
    gemm8p<1, 1><<<dim3(NH1 / 256, B / 256), 512, 0, stream>>>(h3, Wd2_bf, bd2, h4, NH1, NH2, NH2 >> 6);
    // D3: out = h4 @ Wd3^T + bd3       8192x4096 K=2048 -> f32
    gemm8p<0, 0><<<dim3(DIN / 256, B / 256), 512, 0, stream>>>(h4, Wd3_bf, bd3, d_out, DIN, NH1, NH1 >> 6);
}

// Round 4
// 417.389 us; speedup vs baseline: 1.3233x; 1.0584x over previous
//
#include <hip/hip_runtime.h>

// ---------- types / helpers ----------
typedef __attribute__((ext_vector_type(8))) short bf16x8;  // 8 bf16 (4 VGPRs)
typedef __attribute__((ext_vector_type(4))) float f32x4;

__device__ __forceinline__ unsigned short f2bf(float f) {
    union { float f; unsigned int u; } v; v.f = f;
    unsigned int u = v.u;
    unsigned int r = (u + 0x7FFFu + ((u >> 16) & 1u)) >> 16;   // RNE
    return (unsigned short)r;
}
__device__ __forceinline__ float bf2f(unsigned short b) {
    union { unsigned int u; float f; } v; v.u = ((unsigned int)b) << 16;
    return v.f;
}

#define GL16(g, l)                                                             \
    __builtin_amdgcn_global_load_lds(                                          \
        (__attribute__((address_space(1))) void*)(void*)(g),                   \
        (__attribute__((address_space(3))) void*)(void*)(l), 16, 0, 0)

#define SBAR() __builtin_amdgcn_sched_barrier(0)
#define BAR()  do { SBAR(); __builtin_amdgcn_s_barrier(); SBAR(); } while (0)

// ---------- merged f32 -> bf16 casts (one launch, 5 segments) ----------
struct Cast5 {
    const float *s0, *s1, *s2, *s3, *s4;
    unsigned short *d0, *d1, *d2, *d3, *d4;
    int n0, n1, n2, n3, total;   // in float4 units (n4 implied by total)
};
__global__ void castall(Cast5 a) {
    int stride = gridDim.x * blockDim.x;
    for (int i = blockIdx.x * blockDim.x + threadIdx.x; i < a.total; i += stride) {
        int j = i; const float* s; unsigned short* d;
        if (j < a.n0) { s = a.s0; d = a.d0; }
        else { j -= a.n0;
            if (j < a.n1) { s = a.s1; d = a.d1; }
            else { j -= a.n1;
                if (j < a.n2) { s = a.s2; d = a.d2; }
                else { j -= a.n2;
                    if (j < a.n3) { s = a.s3; d = a.d3; }
                    else { j -= a.n3; s = a.s4; d = a.d4; } } } }
        float4 v = ((const float4*)s)[j];
        ushort4 o;
        o.x = f2bf(v.x); o.y = f2bf(v.y); o.z = f2bf(v.z); o.w = f2bf(v.w);
        ((ushort4*)d)[j] = o;
    }
}

// ---------- 8-phase (MP*64 x 256) NT GEMM, pipelined register loads ----------
// MP=4: 256x256 tile, 128KB LDS. MP=2: 128x256 tile, 96KB LDS (for small-N grids).
// 512 thr = 8 waves (2M x 4N). Per-wave (MP*32)x64 output, 2x2 quadrants x (MPx2 frags).
// Quadrant order per K-tile: Q00(a0,b0) Q01(a0,b1) Q11(a1,b1) Q10(a1,b0).
// ds_reads one phase ahead of consumption; QUAD iterates kk OUTER so consecutive
// MFMAs are independent (dep distance MP*2 >= 4).
//   P1: read a1(t);          stage (t+1).A1
//   P2: read b1(t);          stage (t+2).B0; vmcnt(VMN)
//   P3: read a0(t+1);        stage (t+2).A0
//   P4: [QUAD] read b0(t+1); stage (t+2).B1; vmcnt(VMN)
// VMN: ops newer than the half that must have landed = 6 (MP=4) / 5 (MP=2).

template<int RELU, int OUT_BF16, int MP>
__global__ __launch_bounds__(512, 2) void gemm8p(
    const unsigned short* __restrict__ A,   // M x K bf16
    const unsigned short* __restrict__ Bm,  // N x K bf16
    const float* __restrict__ bias,         // N
    void* __restrict__ Cout,                // M x N
    int N, int K, int NT)
{
    constexpr int AHU  = MP * 2048;       // ushorts per A half (MP*32 rows x 64)
    constexpr int BOFF = MP * 8192;       // ushort offset of B region
    __shared__ __align__(16) unsigned short lds[MP * 8192 + 32768];

    const int tid  = threadIdx.x;
    const int lane = tid & 63;
    const int w    = tid >> 6;
    const int wm   = w >> 2;           // 0..1
    const int wn   = w & 3;            // 0..3
    const int bm   = blockIdx.y;
    const int bn   = blockIdx.x;

    const long arow0 = (long)bm * (MP * 64);
    const long brow0 = (long)bn * 256;

    // ---- staging constants ----
    const int sc0 = tid,      sc1 = 512 + tid;
    const int sr0 = sc0 >> 3, sr1 = sc1 >> 3;                      // row in half
    const int so0 = (((sc0 & 7) * 16) ^ ((sr0 & 7) << 4)) >> 1;    // swizzled col (ushort)
    const int so1 = (((sc1 & 7) * 16) ^ ((sr1 & 7) << 4)) >> 1;
    const int soff0 = sr0 * K + so0;
    const int soff1 = sr1 * K + so1;
    const int lb0 = (w * 64) * 8;          // wave-uniform LDS chunk base (ushort idx)
    const int lb1 = (512 + w * 64) * 8;

    // ---- read-side constants ----
    const int cl  = lane & 15;
    const int g16 = (lane >> 4) * 16;                 // byte col of lane's 16B chunk
    const int sw  = (cl & 7) << 4;
    const int cK0 = (g16 ^ sw) >> 1;                  // kk=0 swizzled col (ushort)
    const int cK1 = ((64 + g16) ^ sw) >> 1;           // kk=1
    const int arb = wm * (MP * 16) + cl;              // A row base within half
    const int brb = wn * 32 + cl;                     // B row base within half

    f32x4  acc[2][2][MP][2] = {};
    bf16x8 a0[MP][2], a1[MP][2], b0[2][2], b1[2][2];

#define STAGE_A(t2, h) do {                                                    \
        int b_  = (t2) & 1;                                                    \
        int tt_ = (t2) >= NT ? (t2) - NT : (t2);                               \
        const unsigned short* gb_ = A + (arow0 + (long)(h) * (MP * 32)) * (long)K + (long)tt_ * 64; \
        unsigned short* lh_ = &lds[(b_ * 2 + (h)) * AHU];                      \
        GL16(gb_ + soff0, lh_ + lb0);                                          \
        if constexpr (MP == 4) { GL16(gb_ + soff1, lh_ + lb1); }               \
    } while (0)
#define STAGE_B(t2, h) do {                                                    \
        int b_  = (t2) & 1;                                                    \
        int tt_ = (t2) >= NT ? (t2) - NT : (t2);                               \
        const unsigned short* gb_ = Bm + (brow0 + (long)(h) * 128) * (long)K + (long)tt_ * 64; \
        unsigned short* lh_ = &lds[BOFF + (b_ * 2 + (h)) * 8192];              \
        GL16(gb_ + soff0, lh_ + lb0);                                          \
        GL16(gb_ + soff1, lh_ + lb1);                                          \
    } while (0)

#define READA(AR, mh, b_) do {                                                 \
        const unsigned short* ab_ = &lds[((b_) * 2 + (mh)) * AHU];             \
        _Pragma("unroll") for (int mp_ = 0; mp_ < MP; ++mp_) {                 \
            const unsigned short* rp_ = ab_ + (arb + mp_ * 16) * 64;           \
            AR[mp_][0] = *(const bf16x8*)(rp_ + cK0);                          \
            AR[mp_][1] = *(const bf16x8*)(rp_ + cK1);                          \
        }                                                                      \
    } while (0)
#define READB(BR, nh, b_) do {                                                 \
        const unsigned short* bb_ = &lds[BOFF + ((b_) * 2 + (nh)) * 8192];     \
        _Pragma("unroll") for (int np_ = 0; np_ < 2; ++np_) {                  \
            const unsigned short* rp_ = bb_ + (brb + np_ * 16) * 64;           \
            BR[np_][0] = *(const bf16x8*)(rp_ + cK0);                          \
            BR[np_][1] = *(const bf16x8*)(rp_ + cK1);                          \
        }                                                                      \
    } while (0)
// kk OUTERMOST: consecutive MFMAs independent (dep distance MP*2)
#define QUAD(mh, nh, AR, BR) do {                                              \
        __builtin_amdgcn_s_setprio(1);                                         \
        _Pragma("unroll") for (int kk_ = 0; kk_ < 2; ++kk_)                    \
        _Pragma("unroll") for (int mp_ = 0; mp_ < MP; ++mp_)                   \
        _Pragma("unroll") for (int np_ = 0; np_ < 2; ++np_)                    \
            acc[mh][nh][mp_][np_] = __builtin_amdgcn_mfma_f32_16x16x32_bf16(   \
                AR[mp_][kk_], BR[np_][kk_], acc[mh][nh][mp_][np_], 0, 0, 0);   \
        __builtin_amdgcn_s_setprio(0);                                         \
    } while (0)
#define VMW() do {                                                             \
        SBAR();                                                                \
        if constexpr (MP == 4) asm volatile("s_waitcnt vmcnt(6)" ::: "memory");\
        else                   asm volatile("s_waitcnt vmcnt(5)" ::: "memory");\
        SBAR();                                                                \
    } while (0)

    // ---- prologue: stage tile0 fully + tile1 {B0,A0,B1}; land tile0; preload a0,b0 ----
    STAGE_B(0, 0); STAGE_A(0, 0); STAGE_B(0, 1); STAGE_A(0, 1);
    STAGE_B(1, 0); STAGE_A(1, 0); STAGE_B(1, 1);
    VMW();
    BAR();
    READA(a0, 0, 0);
    READB(b0, 0, 0);

    for (int t = 0; t < NT; ++t) {
        const int b = t & 1;
        // P1
        READA(a1, 1, b);
        STAGE_A(t + 1, 1);
        BAR();
        QUAD(0, 0, a0, b0);
        BAR();
        // P2
        READB(b1, 1, b);
        STAGE_B(t + 2, 0);
        VMW();
        BAR();
        QUAD(0, 1, a0, b1);
        BAR();
        // P3
        READA(a0, 0, b ^ 1);
        STAGE_A(t + 2, 0);
        BAR();
        QUAD(1, 1, a1, b1);
        BAR();
        // P4
        STAGE_B(t + 2, 1);
        VMW();
        BAR();
        QUAD(1, 0, a1, b0);
        READB(b0, 0, b ^ 1);
        BAR();
    }

    // drain wrap stagings before LDS reuse / kernel end
    SBAR(); asm volatile("s_waitcnt vmcnt(0)" ::: "memory"); SBAR();
    BAR();

    // ---- epilogue ----
    const int r4 = (lane >> 4) * 4;
    float bv[2][2];
    #pragma unroll
    for (int nh = 0; nh < 2; ++nh)
        #pragma unroll
        for (int np = 0; np < 2; ++np)
            bv[nh][np] = bias[(long)bn * 256 + nh * 128 + wn * 32 + np * 16 + cl];

    if (OUT_BF16) {
        // LDS-bounce for coalesced bf16 stores
        unsigned short* epi = lds;
        #pragma unroll
        for (int h = 0; h < 2; ++h) {
            if (h) BAR();
            #pragma unroll
            for (int mp = 0; mp < MP; ++mp)
                #pragma unroll
                for (int nh = 0; nh < 2; ++nh)
                    #pragma unroll
                    for (int np = 0; np < 2; ++np)
                        #pragma unroll
                        for (int r = 0; r < 4; ++r) {
                            float v = acc[h][nh][mp][np][r] + bv[nh][np];
                            if (RELU) v = fmaxf(v, 0.f);
                            int lrow = wm * (MP * 16) + mp * 16 + r4 + r;
                            int lcol = nh * 128 + wn * 32 + np * 16 + cl;
                            epi[lrow * 264 + lcol] = f2bf(v);
                        }
            BAR();
            long rowg0 = (long)bm * (MP * 64) + h * (MP * 32);
            #pragma unroll
            for (int i = 0; i < 2 * MP; ++i) {
                int row = (tid >> 5) + i * 16;
                int cc  = (tid & 31) * 8;
                bf16x8 v8 = *(const bf16x8*)&epi[row * 264 + cc];
                *(bf16x8*)((unsigned short*)Cout + (rowg0 + row) * (long)N + (long)bn * 256 + cc) = v8;
            }
        }
    } else {
        #pragma unroll
        for (int mh = 0; mh < 2; ++mh)
            #pragma unroll
            for (int mp = 0; mp < MP; ++mp) {
                long grow = (long)bm * (MP * 64) + mh * (MP * 32) + wm * (MP * 16) + mp * 16 + r4;
                #pragma unroll
                for (int nh = 0; nh < 2; ++nh)
                    #pragma unroll
                    for (int np = 0; np < 2; ++np) {
                        long gcol = (long)bn * 256 + nh * 128 + wn * 32 + np * 16 + cl;
                        #pragma unroll
                        for (int r = 0; r < 4; ++r) {
                            float v = acc[mh][nh][mp][np][r] + bv[nh][np];
                            if (RELU) v = fmaxf(v, 0.f);
                            ((float*)Cout)[(grow + r) * (long)N + gcol] = v;
                        }
                    }
            }
    }
#undef STAGE_A
#undef STAGE_B
#undef READA
#undef READB
#undef QUAD
#undef VMW
}

// ---------- fused: latent(16) -> quantum circuit -> D1 ----------
__global__ __launch_bounds__(256) void latq_d1(
    const unsigned short* __restrict__ h2,  // B x 1024 bf16
    const float* __restrict__ We3,          // 256 x 1024 (rows 0..15 used)
    const float* __restrict__ be3,          // 256
    const float* __restrict__ P,            // 2 x 16 x 3
    const float* __restrict__ Wd1,          // 1024 x 16
    const float* __restrict__ bd1,          // 1024
    unsigned short* __restrict__ h3)        // B x 1024 bf16
{
    __shared__ float zsh[4][16];
    const int lane = threadIdx.x & 63;
    const int wv   = threadIdx.x >> 6;
    const long row = (long)blockIdx.x * 4 + wv;

    float hreg[16];
    const unsigned short* hr = h2 + row * 1024;
    #pragma unroll
    for (int j = 0; j < 16; ++j) hreg[j] = bf2f(hr[lane + 64 * j]);

    float myth = 0.f;
    #pragma unroll
    for (int q = 0; q < 16; ++q) {
        const float* wq = We3 + q * 1024;
        float p = 0.f;
        #pragma unroll
        for (int j = 0; j < 16; ++j) p += hreg[j] * wq[lane + 64 * j];
        #pragma unroll
        for (int o = 32; o; o >>= 1) p += __shfl_xor(p, o, 64);
        if (lane == q) myth = p + be3[q];
    }

    if (lane < 16) {
        const int q = lane;
        float ar = cosf(0.5f * myth), ai = 0.f;
        float br = sinf(0.5f * myth), bi = 0.f;
        #pragma unroll
        for (int l = 0; l < 2; ++l) {
            const float* pp = P + (l * 16 + q) * 3;
            float t, c, s, ar2, ai2, br2, bi2;
            t = 0.5f * pp[0]; c = cosf(t); s = sinf(t);
            ar2 = c * ar + s * bi;  ai2 = c * ai - s * br;
            br2 = c * br + s * ai;  bi2 = c * bi - s * ar;
            ar = ar2; ai = ai2; br = br2; bi = bi2;
            t = 0.5f * pp[1]; c = cosf(t); s = sinf(t);
            ar2 = c * ar - s * br;  ai2 = c * ai - s * bi;
            br2 = s * ar + c * br;  bi2 = s * ai + c * bi;
            ar = ar2; ai = ai2; br = br2; bi = bi2;
            t = 0.5f * pp[2]; c = cosf(t); s = sinf(t);
            ar2 = ar * c + ai * s;  ai2 = ai * c - ar * s;
            br2 = br * c - bi * s;  bi2 = bi * c + br * s;
            ar = ar2; ai = ai2; br = br2; bi = bi2;
        }
        zsh[wv][q] = ar * ar + ai * ai - (br * br + bi * bi);
    }
    __syncthreads();

    float z[16];
    #pragma unroll
    for (int q = 0; q < 16; ++q) z[q] = zsh[wv][q];

    unsigned short* orow = h3 + row * 1024;
    #pragma unroll
    for (int i = 0; i < 16; ++i) {
        int j = lane + 64 * i;
        const float4* wrow = (const float4*)(Wd1 + j * 16);
        float acc = bd1[j];
        #pragma unroll
        for (int qq = 0; qq < 4; ++qq) {
            float4 w4 = wrow[qq];
            acc += z[qq * 4 + 0] * w4.x + z[qq * 4 + 1] * w4.y
                 + z[qq * 4 + 2] * w4.z + z[qq * 4 + 3] * w4.w;
        }
        orow[j] = f2bf(fmaxf(acc, 0.f));
    }
}

// ---------- host ----------
extern "C" void kernel_launch(void* const* d_in, const int* in_sizes, int n_in,
                              void* d_out, int out_size, void* d_ws, size_t ws_size,
                              hipStream_t stream) {
    const float* x   = (const float*)d_in[0];
    const float* We1 = (const float*)d_in[1];
    const float* be1 = (const float*)d_in[2];
    const float* We2 = (const float*)d_in[3];
    const float* be2 = (const float*)d_in[4];
    const float* We3 = (const float*)d_in[5];
    const float* be3 = (const float*)d_in[6];
    const float* P   = (const float*)d_in[7];
    const float* Wd1 = (const float*)d_in[8];
    const float* bd1 = (const float*)d_in[9];
    const float* Wd2 = (const float*)d_in[10];
    const float* bd2 = (const float*)d_in[11];
    const float* Wd3 = (const float*)d_in[12];
    const float* bd3 = (const float*)d_in[13];

    const int B = 8192, DIN = 4096, NH1 = 2048, NH2 = 1024;

    char* w = (char*)d_ws;
    unsigned short* x_bf   = (unsigned short*)(w);                    // 64MB
    unsigned short* h4     = x_bf;                                    // alias (x dead after G1)
    unsigned short* We1_bf = (unsigned short*)(w + 67108864L);        // 16MB
    unsigned short* We2_bf = (unsigned short*)(w + 83886080L);        // 4MB
    unsigned short* Wd2_bf = (unsigned short*)(w + 88080384L);        // 4MB
    unsigned short* Wd3_bf = (unsigned short*)(w + 92274688L);        // 16MB
    unsigned short* h1     = (unsigned short*)(w + 109051904L);       // 32MB
    unsigned short* h3     = h1;                                      // alias (h1 dead after G2)
    unsigned short* h2     = (unsigned short*)(w + 142606336L);       // 16MB

    // merged casts (one launch)
    Cast5 ca;
    ca.s0 = x;   ca.d0 = x_bf;   ca.n0 = (int)((long)B * DIN / 4);
    ca.s1 = We1; ca.d1 = We1_bf; ca.n1 = (int)((long)NH1 * DIN / 4);
    ca.s2 = We2; ca.d2 = We2_bf; ca.n2 = (int)((long)NH2 * NH1 / 4);
    ca.s3 = Wd2; ca.d3 = Wd2_bf; ca.n3 = (int)((long)NH1 * NH2 / 4);
    ca.s4 = Wd3; ca.d4 = Wd3_bf;
    ca.total = ca.n0 + ca.n1 + ca.n2 + ca.n3 + (int)((long)DIN * NH1 / 4);
    castall<<<2048, 256, 0, stream>>>(ca);

    // G1: h1 = relu(x @ We1^T + be1)   8192x2048 K=4096   (256x256, 256 blocks)
    gemm8p<1, 1, 4><<<dim3(NH1 / 256, B / 256), 512, 0, stream>>>(x_bf, We1_bf, be1, h1, NH1, DIN, DIN >> 6);
    // G2: h2 = relu(h1 @ We2^T + be2)  8192x1024 K=2048   (128x256, 256 blocks)
    gemm8p<1, 1, 2><<<dim3(NH2 / 256, B / 128), 512, 0, stream>>>(h1, We2_bf, be2, h2, NH2, NH1, NH1 >> 6);
    // latent -> quantum -> D1
    latq_d1<<<dim3(B / 4), 256, 0, stream>>>(h2, We3, be3, P, Wd1, bd1, h3);
    // D2: h4 = relu(h3 @ Wd2^T + bd2)  8192x2048 K=1024   (256x256, 256 blocks)
    gemm8p<1, 1, 4><<<dim3(NH1 / 256, B / 256), 512, 0, stream>>>(h3, Wd2_bf, bd2, h4, NH1, NH2, NH2 >> 6);
    // D3: out = h4 @ Wd3^T + bd3       8192x4096 K=2048 -> f32  (512 blocks)
    gemm8p<0, 0, 4><<<dim3(DIN / 256, B / 256), 512, 0, stream>>>(h4, Wd3_bf, bd3, d_out, DIN, NH1, NH1 >> 6);
}

// Round 5
// 388.607 us; speedup vs baseline: 1.4213x; 1.0741x over previous
//
#include <hip/hip_runtime.h>

// ---------- types / helpers ----------
typedef __attribute__((ext_vector_type(8))) short bf16x8;  // 8 bf16 (4 VGPRs)
typedef __attribute__((ext_vector_type(4))) float f32x4;

__device__ __forceinline__ unsigned short f2bf(float f) {
    union { float f; unsigned int u; } v; v.f = f;
    unsigned int u = v.u;
    unsigned int r = (u + 0x7FFFu + ((u >> 16) & 1u)) >> 16;   // RNE
    return (unsigned short)r;
}
__device__ __forceinline__ float bf2f(unsigned short b) {
    union { unsigned int u; float f; } v; v.u = ((unsigned int)b) << 16;
    return v.f;
}

#define GL16(g, l)                                                             \
    __builtin_amdgcn_global_load_lds(                                          \
        (__attribute__((address_space(1))) void*)(void*)(g),                   \
        (__attribute__((address_space(3))) void*)(void*)(l), 16, 0, 0)

#define SBAR() __builtin_amdgcn_sched_barrier(0)
#define BAR()  do { SBAR(); __builtin_amdgcn_s_barrier(); SBAR(); } while (0)

// ---------- merged f32 -> bf16 casts (one launch, 5 segments) ----------
struct Cast5 {
    const float *s0, *s1, *s2, *s3, *s4;
    unsigned short *d0, *d1, *d2, *d3, *d4;
    int n0, n1, n2, n3, total;
};
__global__ void castall(Cast5 a) {
    int stride = gridDim.x * blockDim.x;
    for (int i = blockIdx.x * blockDim.x + threadIdx.x; i < a.total; i += stride) {
        int j = i; const float* s; unsigned short* d;
        if (j < a.n0) { s = a.s0; d = a.d0; }
        else { j -= a.n0;
            if (j < a.n1) { s = a.s1; d = a.d1; }
            else { j -= a.n1;
                if (j < a.n2) { s = a.s2; d = a.d2; }
                else { j -= a.n2;
                    if (j < a.n3) { s = a.s3; d = a.d3; }
                    else { j -= a.n3; s = a.s4; d = a.d4; } } } }
        float4 v = ((const float4*)s)[j];
        ushort4 o;
        o.x = f2bf(v.x); o.y = f2bf(v.y); o.z = f2bf(v.z); o.w = f2bf(v.w);
        ((ushort4*)d)[j] = o;
    }
}

// ---------- 8-phase (MP*64 x 256) NT GEMM ----------
// 512 thr = 8 waves (2M x 4N). K-loop unrolled x2 so buffer parity is
// COMPILE-TIME: all ds_reads are base+imm, staging via scalar column
// pointers (SGPR) + one per-lane 32-bit offset. 1 barrier per phase.
// Phases per K-tile t (parity PAR):
//   P1: read a1(t);  stage A1(t+1);          BAR; QUAD(0,0)(a0,b0)
//   P2: read b1(t);  stage B0(t+2); VMW;     BAR; QUAD(0,1)(a0,b1)
//   P3: read a0(t+1);stage A0(t+2);          BAR; QUAD(1,1)(a1,b1)
//   P4:              stage B1(t+2); VMW;     BAR; QUAD(1,0)(a1,b0); read b0(t+1)
// Ledger (MP=4, 2 ops/stage): VMW(6)@P2(t) -> A0(t+1)+older landed;
// VMW(6)@P4(t) -> A1(t+1)+older landed. MP=2 (A=1 op): both are VMW(5).

template<int RELU, int OUT_BF16, int MP>
__global__ __launch_bounds__(512, 2) void gemm8p(
    const unsigned short* __restrict__ A,   // M x K bf16
    const unsigned short* __restrict__ Bm,  // N x K bf16
    const float* __restrict__ bias,         // N
    void* __restrict__ Cout,                // M x N
    int N, int K, int NT)
{
    constexpr int AHU  = MP * 2048;       // ushorts per A half (MP*32 rows x 64)
    constexpr int BOFF = MP * 8192;       // ushort offset of B region
    __shared__ __align__(16) unsigned short lds[MP * 8192 + 32768];

    const int tid  = threadIdx.x;
    const int lane = tid & 63;
    const int w    = tid >> 6;
    const int wm   = w >> 2;           // 0..1
    const int wn   = w & 3;            // 0..3
    const int bm   = blockIdx.y;
    const int bn   = blockIdx.x;

    // ---- block panel bases (uniform -> SGPR) ----
    const unsigned short* gA = A  + (long)bm * (MP * 64) * K;
    const unsigned short* gB = Bm + (long)bn * 256 * K;

    // ---- staging: per-lane byte offset within a half-panel ----
    const int sr0 = tid >> 3;                                      // row 0..63
    const int so0 = (((tid & 7) * 16) ^ ((sr0 & 7) << 4)) >> 1;    // swizzled col (ushort)
    const int loff = (sr0 * K + so0) * 2;                          // bytes
    const int ch1  = K * 128;                                      // +64 rows, bytes (uniform)
    const int lb0 = (w * 64) * 8;            // wave-uniform LDS chunk base (ushort idx)
    const int lb1 = (512 + w * 64) * 8;

    // ---- LDS read bases (per-lane VGPR, byte) ----
    const int cl  = lane & 15;
    const int g16 = (lane >> 4) * 16;
    const int sw  = (cl & 7) << 4;
    const int cK0 = (g16 ^ sw) >> 1;
    const int cK1 = ((64 + g16) ^ sw) >> 1;
    const int arb = wm * (MP * 16) + cl;
    const int brb = wn * 32 + cl;
    const int aIdx0 = (arb * 64 + cK0) * 2;
    const int aIdx1 = (arb * 64 + cK1) * 2;
    const int bIdx0 = (BOFF + brb * 64 + cK0) * 2;
    const int bIdx1 = (BOFF + brb * 64 + cK1) * 2;

    f32x4  acc[2][2][MP][2] = {};
    bf16x8 a0[MP][2], a1[MP][2], b0[2][2], b1[2][2];

#define GLA_(SP, DI) do {                                                      \
        GL16((const char*)(SP) + loff, &lds[0] + (DI) + lb0);                  \
        if constexpr (MP == 4) {                                               \
            GL16((const char*)(SP) + loff + ch1, &lds[0] + (DI) + lb1); }      \
    } while (0)
#define GLB_(SP, DI) do {                                                      \
        GL16((const char*)(SP) + loff, &lds[0] + (DI) + lb0);                  \
        GL16((const char*)(SP) + loff + ch1, &lds[0] + (DI) + lb1);            \
    } while (0)

#define READA_(AR, MH, PAR) do {                                               \
        _Pragma("unroll") for (int mp_ = 0; mp_ < MP; ++mp_) {                 \
            AR[mp_][0] = *(const bf16x8*)((const char*)lds + aIdx0 +           \
                         (((PAR)*2+(MH))*AHU*2 + mp_*2048));                   \
            AR[mp_][1] = *(const bf16x8*)((const char*)lds + aIdx1 +           \
                         (((PAR)*2+(MH))*AHU*2 + mp_*2048));                   \
        } } while (0)
#define READB_(BR, NH, PAR) do {                                               \
        _Pragma("unroll") for (int np_ = 0; np_ < 2; ++np_) {                  \
            BR[np_][0] = *(const bf16x8*)((const char*)lds + bIdx0 +           \
                         (((PAR)*2+(NH))*16384 + np_*2048));                   \
            BR[np_][1] = *(const bf16x8*)((const char*)lds + bIdx1 +           \
                         (((PAR)*2+(NH))*16384 + np_*2048));                   \
        } } while (0)
#define QUAD(mh, nh, AR, BR) do {                                              \
        __builtin_amdgcn_s_setprio(1);                                         \
        _Pragma("unroll") for (int kk_ = 0; kk_ < 2; ++kk_)                    \
        _Pragma("unroll") for (int mp_ = 0; mp_ < MP; ++mp_)                   \
        _Pragma("unroll") for (int np_ = 0; np_ < 2; ++np_)                    \
            acc[mh][nh][mp_][np_] = __builtin_amdgcn_mfma_f32_16x16x32_bf16(   \
                AR[mp_][kk_], BR[np_][kk_], acc[mh][nh][mp_][np_], 0, 0, 0);   \
        __builtin_amdgcn_s_setprio(0);                                         \
    } while (0)
#define VMW() do {                                                             \
        SBAR();                                                                \
        if constexpr (MP == 4) asm volatile("s_waitcnt vmcnt(6)" ::: "memory");\
        else                   asm volatile("s_waitcnt vmcnt(5)" ::: "memory");\
        SBAR();                                                                \
    } while (0)

    // ---- prologue: tile0 {B0,A0,B1,A1} + tile1 {B0,A0,B1} (this op order!) ----
    GLB_(gB,                      BOFF + 0);
    GLA_(gA,                      0);
    GLB_(gB + (long)128 * K,      BOFF + 8192);
    GLA_(gA + (long)(MP*32) * K,  AHU);
    GLB_(gB + 64,                 BOFF + 2*8192);
    GLA_(gA + 64,                 2*AHU);
    GLB_(gB + (long)128 * K + 64, BOFF + 3*8192);
    VMW();
    BAR();
    READA_(a0, 0, 0);
    READB_(b0, 0, 0);

    // ---- running scalar column pointers ----
    const unsigned short* sA1 = gA + (long)(MP*32) * K + 64;   // col 1
    const unsigned short* sA0 = gA + 128;                      // col 2
    const unsigned short* sB0 = gB + 128;                      // col 2
    const unsigned short* sB1 = gB + (long)128 * K + 128;      // col 2

#define KTILE(T, PAR) do {                                                     \
        const int adv1_ = ((T) + 2 < NT) ? 64 : 0;                             \
        const int adv2_ = ((T) + 3 < NT) ? 64 : 0;                             \
        /* P1 */                                                               \
        READA_(a1, 1, PAR);                                                    \
        GLA_(sA1, (((PAR)^1)*2+1)*AHU); sA1 += adv1_;                          \
        BAR();                                                                 \
        QUAD(0, 0, a0, b0);                                                    \
        /* P2 */                                                               \
        READB_(b1, 1, PAR);                                                    \
        GLB_(sB0, BOFF + (PAR)*2*8192); sB0 += adv2_;                          \
        VMW();                                                                 \
        BAR();                                                                 \
        QUAD(0, 1, a0, b1);                                                    \
        /* P3 */                                                               \
        READA_(a0, 0, (PAR)^1);                                                \
        GLA_(sA0, (PAR)*2*AHU); sA0 += adv2_;                                  \
        BAR();                                                                 \
        QUAD(1, 1, a1, b1);                                                    \
        /* P4 */                                                               \
        GLB_(sB1, BOFF + ((PAR)*2+1)*8192); sB1 += adv2_;                      \
        VMW();                                                                 \
        BAR();                                                                 \
        QUAD(1, 0, a1, b0);                                                    \
        READB_(b0, 0, (PAR)^1);                                                \
    } while (0)

    for (int t = 0; t < NT; t += 2) {
        KTILE(t, 0);
        KTILE(t + 1, 1);
    }

    // drain clamped wrap-stagings before LDS reuse / kernel end
    SBAR(); asm volatile("s_waitcnt vmcnt(0)" ::: "memory"); SBAR();
    BAR();

    // ---- epilogue ----
    const int r4 = (lane >> 4) * 4;
    float bv[2][2];
    #pragma unroll
    for (int nh = 0; nh < 2; ++nh)
        #pragma unroll
        for (int np = 0; np < 2; ++np)
            bv[nh][np] = bias[(long)bn * 256 + nh * 128 + wn * 32 + np * 16 + cl];

    if (OUT_BF16) {
        unsigned short* epi = lds;
        #pragma unroll
        for (int h = 0; h < 2; ++h) {
            if (h) BAR();
            #pragma unroll
            for (int mp = 0; mp < MP; ++mp)
                #pragma unroll
                for (int nh = 0; nh < 2; ++nh)
                    #pragma unroll
                    for (int np = 0; np < 2; ++np)
                        #pragma unroll
                        for (int r = 0; r < 4; ++r) {
                            float v = acc[h][nh][mp][np][r] + bv[nh][np];
                            if (RELU) v = fmaxf(v, 0.f);
                            int lrow = wm * (MP * 16) + mp * 16 + r4 + r;
                            int lcol = nh * 128 + wn * 32 + np * 16 + cl;
                            epi[lrow * 264 + lcol] = f2bf(v);
                        }
            BAR();
            long rowg0 = (long)bm * (MP * 64) + h * (MP * 32);
            #pragma unroll
            for (int i = 0; i < 2 * MP; ++i) {
                int row = (tid >> 5) + i * 16;
                int cc  = (tid & 31) * 8;
                bf16x8 v8 = *(const bf16x8*)&epi[row * 264 + cc];
                *(bf16x8*)((unsigned short*)Cout + (rowg0 + row) * (long)N + (long)bn * 256 + cc) = v8;
            }
        }
    } else {
        #pragma unroll
        for (int mh = 0; mh < 2; ++mh)
            #pragma unroll
            for (int mp = 0; mp < MP; ++mp) {
                long grow = (long)bm * (MP * 64) + mh * (MP * 32) + wm * (MP * 16) + mp * 16 + r4;
                #pragma unroll
                for (int nh = 0; nh < 2; ++nh)
                    #pragma unroll
                    for (int np = 0; np < 2; ++np) {
                        long gcol = (long)bn * 256 + nh * 128 + wn * 32 + np * 16 + cl;
                        #pragma unroll
                        for (int r = 0; r < 4; ++r) {
                            float v = acc[mh][nh][mp][np][r] + bv[nh][np];
                            if (RELU) v = fmaxf(v, 0.f);
                            ((float*)Cout)[(grow + r) * (long)N + gcol] = v;
                        }
                    }
            }
    }
#undef GLA_
#undef GLB_
#undef READA_
#undef READB_
#undef QUAD
#undef VMW
#undef KTILE
}

// ---------- fused: latent(16) -> quantum circuit -> D1 ----------
__global__ __launch_bounds__(256) void latq_d1(
    const unsigned short* __restrict__ h2,  // B x 1024 bf16
    const float* __restrict__ We3,          // 256 x 1024 (rows 0..15 used)
    const float* __restrict__ be3,          // 256
    const float* __restrict__ P,            // 2 x 16 x 3
    const float* __restrict__ Wd1,          // 1024 x 16
    const float* __restrict__ bd1,          // 1024
    unsigned short* __restrict__ h3)        // B x 1024 bf16
{
    __shared__ float zsh[4][16];
    const int lane = threadIdx.x & 63;
    const int wv   = threadIdx.x >> 6;
    const long row = (long)blockIdx.x * 4 + wv;

    float hreg[16];
    const unsigned short* hr = h2 + row * 1024;
    #pragma unroll
    for (int j = 0; j < 16; ++j) hreg[j] = bf2f(hr[lane + 64 * j]);

    float myth = 0.f;
    #pragma unroll
    for (int q = 0; q < 16; ++q) {
        const float* wq = We3 + q * 1024;
        float p = 0.f;
        #pragma unroll
        for (int j = 0; j < 16; ++j) p += hreg[j] * wq[lane + 64 * j];
        #pragma unroll
        for (int o = 32; o; o >>= 1) p += __shfl_xor(p, o, 64);
        if (lane == q) myth = p + be3[q];
    }

    if (lane < 16) {
        const int q = lane;
        float ar = cosf(0.5f * myth), ai = 0.f;
        float br = sinf(0.5f * myth), bi = 0.f;
        #pragma unroll
        for (int l = 0; l < 2; ++l) {
            const float* pp = P + (l * 16 + q) * 3;
            float t, c, s, ar2, ai2, br2, bi2;
            t = 0.5f * pp[0]; c = cosf(t); s = sinf(t);
            ar2 = c * ar + s * bi;  ai2 = c * ai - s * br;
            br2 = c * br + s * ai;  bi2 = c * bi - s * ar;
            ar = ar2; ai = ai2; br = br2; bi = bi2;
            t = 0.5f * pp[1]; c = cosf(t); s = sinf(t);
            ar2 = c * ar - s * br;  ai2 = c * ai - s * bi;
            br2 = s * ar + c * br;  bi2 = s * ai + c * bi;
            ar = ar2; ai = ai2; br = br2; bi = bi2;
            t = 0.5f * pp[2]; c = cosf(t); s = sinf(t);
            ar2 = ar * c + ai * s;  ai2 = ai * c - ar * s;
            br2 = br * c - bi * s;  bi2 = bi * c + br * s;
            ar = ar2; ai = ai2; br = br2; bi = bi2;
        }
        zsh[wv][q] = ar * ar + ai * ai - (br * br + bi * bi);
    }
    __syncthreads();

    float z[16];
    #pragma unroll
    for (int q = 0; q < 16; ++q) z[q] = zsh[wv][q];

    unsigned short* orow = h3 + row * 1024;
    #pragma unroll
    for (int i = 0; i < 16; ++i) {
        int j = lane + 64 * i;
        const float4* wrow = (const float4*)(Wd1 + j * 16);
        float acc = bd1[j];
        #pragma unroll
        for (int qq = 0; qq < 4; ++qq) {
            float4 w4 = wrow[qq];
            acc += z[qq * 4 + 0] * w4.x + z[qq * 4 + 1] * w4.y
                 + z[qq * 4 + 2] * w4.z + z[qq * 4 + 3] * w4.w;
        }
        orow[j] = f2bf(fmaxf(acc, 0.f));
    }
}

// ---------- host ----------
extern "C" void kernel_launch(void* const* d_in, const int* in_sizes, int n_in,
                              void* d_out, int out_size, void* d_ws, size_t ws_size,
                              hipStream_t stream) {
    const float* x   = (const float*)d_in[0];
    const float* We1 = (const float*)d_in[1];
    const float* be1 = (const float*)d_in[2];
    const float* We2 = (const float*)d_in[3];
    const float* be2 = (const float*)d_in[4];
    const float* We3 = (const float*)d_in[5];
    const float* be3 = (const float*)d_in[6];
    const float* P   = (const float*)d_in[7];
    const float* Wd1 = (const float*)d_in[8];
    const float* bd1 = (const float*)d_in[9];
    const float* Wd2 = (const float*)d_in[10];
    const float* bd2 = (const float*)d_in[11];
    const float* Wd3 = (const float*)d_in[12];
    const float* bd3 = (const float*)d_in[13];

    const int B = 8192, DIN = 4096, NH1 = 2048, NH2 = 1024;

    char* w = (char*)d_ws;
    unsigned short* x_bf   = (unsigned short*)(w);                    // 64MB
    unsigned short* h4     = x_bf;                                    // alias (x dead after G1)
    unsigned short* We1_bf = (unsigned short*)(w + 67108864L);        // 16MB
    unsigned short* We2_bf = (unsigned short*)(w + 83886080L);        // 4MB
    unsigned short* Wd2_bf = (unsigned short*)(w + 88080384L);        // 4MB
    unsigned short* Wd3_bf = (unsigned short*)(w + 92274688L);        // 16MB
    unsigned short* h1     = (unsigned short*)(w + 109051904L);       // 32MB
    unsigned short* h3     = h1;                                      // alias (h1 dead after G2)
    unsigned short* h2     = (unsigned short*)(w + 142606336L);       // 16MB

    Cast5 ca;
    ca.s0 = x;   ca.d0 = x_bf;   ca.n0 = (int)((long)B * DIN / 4);
    ca.s1 = We1; ca.d1 = We1_bf; ca.n1 = (int)((long)NH1 * DIN / 4);
    ca.s2 = We2; ca.d2 = We2_bf; ca.n2 = (int)((long)NH2 * NH1 / 4);
    ca.s3 = Wd2; ca.d3 = Wd2_bf; ca.n3 = (int)((long)NH1 * NH2 / 4);
    ca.s4 = Wd3; ca.d4 = Wd3_bf;
    ca.total = ca.n0 + ca.n1 + ca.n2 + ca.n3 + (int)((long)DIN * NH1 / 4);
    castall<<<2048, 256, 0, stream>>>(ca);

    // G1: h1 = relu(x @ We1^T + be1)   8192x2048 K=4096   (256x256)
    gemm8p<1, 1, 4><<<dim3(NH1 / 256, B / 256), 512, 0, stream>>>(x_bf, We1_bf, be1, h1, NH1, DIN, DIN >> 6);
    // G2: h2 = relu(h1 @ We2^T + be2)  8192x1024 K=2048   (128x256)
    gemm8p<1, 1, 2><<<dim3(NH2 / 256, B / 128), 512, 0, stream>>>(h1, We2_bf, be2, h2, NH2, NH1, NH1 >> 6);
    // latent -> quantum -> D1
    latq_d1<<<dim3(B / 4), 256, 0, stream>>>(h2, We3, be3, P, Wd1, bd1, h3);
    // D2: h4 = relu(h3 @ Wd2^T + bd2)  8192x2048 K=1024   (256x256)
    gemm8p<1, 1, 4><<<dim3(NH1 / 256, B / 256), 512, 0, stream>>>(h3, Wd2_bf, bd2, h4, NH1, NH2, NH2 >> 6);
    // D3: out = h4 @ Wd3^T + bd3       8192x4096 K=2048 -> f32
    gemm8p<0, 0, 4><<<dim3(DIN / 256, B / 256), 512, 0, stream>>>(h4, Wd3_bf, bd3, d_out, DIN, NH1, NH1 >> 6);
}

// Round 6
// 387.886 us; speedup vs baseline: 1.4239x; 1.0019x over previous
//
#include <hip/hip_runtime.h>

// ---------- types / helpers ----------
typedef __attribute__((ext_vector_type(8))) short bf16x8;  // 8 bf16 (4 VGPRs)
typedef __attribute__((ext_vector_type(4))) float f32x4;

__device__ __forceinline__ unsigned short f2bf(float f) {
    union { float f; unsigned int u; } v; v.f = f;
    unsigned int u = v.u;
    unsigned int r = (u + 0x7FFFu + ((u >> 16) & 1u)) >> 16;   // RNE
    return (unsigned short)r;
}
__device__ __forceinline__ float bf2f(unsigned short b) {
    union { unsigned int u; float f; } v; v.u = ((unsigned int)b) << 16;
    return v.f;
}

#define GL16(g, l)                                                             \
    __builtin_amdgcn_global_load_lds(                                          \
        (__attribute__((address_space(1))) void*)(void*)(g),                   \
        (__attribute__((address_space(3))) void*)(void*)(l), 16, 0, 0)

// plain barrier: no sched_barrier pinning (m141: blanket order-pinning defeats
// the compiler's cross-phase pipelining). Ordering safety comes from the
// vmcnt asm "memory" clobbers (publish) and LDS-op aliasing (WAR).
#define BAR()  __builtin_amdgcn_s_barrier()
#define LGKM0() asm volatile("s_waitcnt lgkmcnt(0)" ::: "memory")

// ---------- merged f32 -> bf16 casts (one launch, 5 segments) ----------
struct Cast5 {
    const float *s0, *s1, *s2, *s3, *s4;
    unsigned short *d0, *d1, *d2, *d3, *d4;
    int n0, n1, n2, n3, total;
};
__global__ void castall(Cast5 a) {
    int stride = gridDim.x * blockDim.x;
    for (int i = blockIdx.x * blockDim.x + threadIdx.x; i < a.total; i += stride) {
        int j = i; const float* s; unsigned short* d;
        if (j < a.n0) { s = a.s0; d = a.d0; }
        else { j -= a.n0;
            if (j < a.n1) { s = a.s1; d = a.d1; }
            else { j -= a.n1;
                if (j < a.n2) { s = a.s2; d = a.d2; }
                else { j -= a.n2;
                    if (j < a.n3) { s = a.s3; d = a.d3; }
                    else { j -= a.n3; s = a.s4; d = a.d4; } } } }
        float4 v = ((const float4*)s)[j];
        ushort4 o;
        o.x = f2bf(v.x); o.y = f2bf(v.y); o.z = f2bf(v.z); o.w = f2bf(v.w);
        ((ushort4*)d)[j] = o;
    }
}

// ---------- 8-phase (MP*64 x 256) NT GEMM ----------
// 512 thr = 8 waves (2M x 4N). K-loop unrolled x2 so buffer parity is
// COMPILE-TIME: all ds_reads are base+imm, staging via scalar column
// pointers (SGPR) + one per-lane 32-bit offset. 1 barrier per phase.
// Phases per K-tile t (parity PAR):
//   P1: read a1(t);  stage A1(t+1);          BAR; QUAD(0,0)(a0,b0)
//   P2: read b1(t);  stage B0(t+2); VMW;     BAR; QUAD(0,1)(a0,b1)
//   P3: read a0(t+1);stage A0(t+2);          BAR; QUAD(1,1)(a1,b1)
//   P4:              stage B1(t+2); VMW;     BAR; QUAD(1,0)(a1,b0); read b0(t+1)
// Ledger (MP=4, 2 ops/stage): VMW(6)@P2(t) -> A0(t+1)+older landed;
// VMW(6)@P4(t) -> A1(t+1)+older landed. MP=2 (A=1 op): both are VMW(5).

template<int RELU, int OUT_BF16, int MP>
__global__ __launch_bounds__(512, 2) void gemm8p(
    const unsigned short* __restrict__ A,   // M x K bf16
    const unsigned short* __restrict__ Bm,  // N x K bf16
    const float* __restrict__ bias,         // N
    void* __restrict__ Cout,                // M x N
    int N, int K, int NT)
{
    constexpr int AHU  = MP * 2048;       // ushorts per A half (MP*32 rows x 64)
    constexpr int BOFF = MP * 8192;       // ushort offset of B region
    __shared__ __align__(16) unsigned short lds[MP * 8192 + 32768];

    const int tid  = threadIdx.x;
    const int lane = tid & 63;
    const int w    = tid >> 6;
    const int wm   = w >> 2;           // 0..1
    const int wn   = w & 3;            // 0..3
    const int bm   = blockIdx.y;
    const int bn   = blockIdx.x;

    // ---- block panel bases (uniform -> SGPR) ----
    const unsigned short* gA = A  + (long)bm * (MP * 64) * K;
    const unsigned short* gB = Bm + (long)bn * 256 * K;

    // ---- staging: per-lane byte offset within a half-panel ----
    const int sr0 = tid >> 3;                                      // row 0..63
    const int so0 = (((tid & 7) * 16) ^ ((sr0 & 7) << 4)) >> 1;    // swizzled col (ushort)
    const int loff = (sr0 * K + so0) * 2;                          // bytes
    const int ch1  = K * 128;                                      // +64 rows, bytes (uniform)
    const int lb0 = (w * 64) * 8;            // wave-uniform LDS chunk base (ushort idx)
    const int lb1 = (512 + w * 64) * 8;

    // ---- LDS read bases (per-lane VGPR, byte) ----
    const int cl  = lane & 15;
    const int g16 = (lane >> 4) * 16;
    const int sw  = (cl & 7) << 4;
    const int cK0 = (g16 ^ sw) >> 1;
    const int cK1 = ((64 + g16) ^ sw) >> 1;
    const int arb = wm * (MP * 16) + cl;
    const int brb = wn * 32 + cl;
    const int aIdx0 = (arb * 64 + cK0) * 2;
    const int aIdx1 = (arb * 64 + cK1) * 2;
    const int bIdx0 = (BOFF + brb * 64 + cK0) * 2;
    const int bIdx1 = (BOFF + brb * 64 + cK1) * 2;

    f32x4  acc[2][2][MP][2] = {};
    bf16x8 a0[MP][2], a1[MP][2], b0[2][2], b1[2][2];

#define GLA_(SP, DI) do {                                                      \
        GL16((const char*)(SP) + loff, &lds[0] + (DI) + lb0);                  \
        if constexpr (MP == 4) {                                               \
            GL16((const char*)(SP) + loff + ch1, &lds[0] + (DI) + lb1); }      \
    } while (0)
#define GLB_(SP, DI) do {                                                      \
        GL16((const char*)(SP) + loff, &lds[0] + (DI) + lb0);                  \
        GL16((const char*)(SP) + loff + ch1, &lds[0] + (DI) + lb1);            \
    } while (0)

#define READA_(AR, MH, PAR) do {                                               \
        _Pragma("unroll") for (int mp_ = 0; mp_ < MP; ++mp_) {                 \
            AR[mp_][0] = *(const bf16x8*)((const char*)lds + aIdx0 +           \
                         (((PAR)*2+(MH))*AHU*2 + mp_*2048));                   \
            AR[mp_][1] = *(const bf16x8*)((const char*)lds + aIdx1 +           \
                         (((PAR)*2+(MH))*AHU*2 + mp_*2048));                   \
        } } while (0)
#define READB_(BR, NH, PAR) do {                                               \
        _Pragma("unroll") for (int np_ = 0; np_ < 2; ++np_) {                  \
            BR[np_][0] = *(const bf16x8*)((const char*)lds + bIdx0 +           \
                         (((PAR)*2+(NH))*16384 + np_*2048));                   \
            BR[np_][1] = *(const bf16x8*)((const char*)lds + bIdx1 +           \
                         (((PAR)*2+(NH))*16384 + np_*2048));                   \
        } } while (0)
#define QUAD(mh, nh, AR, BR) do {                                              \
        __builtin_amdgcn_s_setprio(1);                                         \
        _Pragma("unroll") for (int kk_ = 0; kk_ < 2; ++kk_)                    \
        _Pragma("unroll") for (int mp_ = 0; mp_ < MP; ++mp_)                   \
        _Pragma("unroll") for (int np_ = 0; np_ < 2; ++np_)                    \
            acc[mh][nh][mp_][np_] = __builtin_amdgcn_mfma_f32_16x16x32_bf16(   \
                AR[mp_][kk_], BR[np_][kk_], acc[mh][nh][mp_][np_], 0, 0, 0);   \
        __builtin_amdgcn_s_setprio(0);                                         \
    } while (0)
#define VMW() do {                                                             \
        if constexpr (MP == 4) asm volatile("s_waitcnt vmcnt(6)" ::: "memory");\
        else                   asm volatile("s_waitcnt vmcnt(5)" ::: "memory");\
    } while (0)

    // ---- prologue: tile0 {B0,A0,B1,A1} + tile1 {B0,A0,B1} (this op order!) ----
    GLB_(gB,                      BOFF + 0);
    GLA_(gA,                      0);
    GLB_(gB + (long)128 * K,      BOFF + 8192);
    GLA_(gA + (long)(MP*32) * K,  AHU);
    GLB_(gB + 64,                 BOFF + 2*8192);
    GLA_(gA + 64,                 2*AHU);
    GLB_(gB + (long)128 * K + 64, BOFF + 3*8192);
    VMW();
    BAR();
    READA_(a0, 0, 0);
    READB_(b0, 0, 0);

    // ---- running scalar column pointers ----
    const unsigned short* sA1 = gA + (long)(MP*32) * K + 64;   // col 1
    const unsigned short* sA0 = gA + 128;                      // col 2
    const unsigned short* sB0 = gB + 128;                      // col 2
    const unsigned short* sB1 = gB + (long)128 * K + 128;      // col 2

#define KTILE(T, PAR) do {                                                     \
        const int adv1_ = ((T) + 2 < NT) ? 64 : 0;                             \
        const int adv2_ = ((T) + 3 < NT) ? 64 : 0;                             \
        /* P1 */                                                               \
        READA_(a1, 1, PAR);                                                    \
        GLA_(sA1, (((PAR)^1)*2+1)*AHU); sA1 += adv1_;                          \
        BAR();                                                                 \
        QUAD(0, 0, a0, b0);                                                    \
        /* P2 */                                                               \
        READB_(b1, 1, PAR);                                                    \
        GLB_(sB0, BOFF + (PAR)*2*8192); sB0 += adv2_;                          \
        VMW();                                                                 \
        BAR();                                                                 \
        QUAD(0, 1, a0, b1);                                                    \
        /* P3 */                                                               \
        READA_(a0, 0, (PAR)^1);                                                \
        GLA_(sA0, (PAR)*2*AHU); sA0 += adv2_;                                  \
        BAR();                                                                 \
        QUAD(1, 1, a1, b1);                                                    \
        /* P4 */                                                               \
        GLB_(sB1, BOFF + ((PAR)*2+1)*8192); sB1 += adv2_;                      \
        VMW();                                                                 \
        BAR();                                                                 \
        QUAD(1, 0, a1, b0);                                                    \
        READB_(b0, 0, (PAR)^1);                                                \
    } while (0)

    for (int t = 0; t < NT; t += 2) {
        KTILE(t, 0);
        KTILE(t + 1, 1);
    }

    // drain clamped wrap-stagings before LDS reuse / kernel end
    asm volatile("s_waitcnt vmcnt(0)" ::: "memory");
    BAR();

    // ---- epilogue ----
    const int r4 = (lane >> 4) * 4;
    float bv[2][2];
    #pragma unroll
    for (int nh = 0; nh < 2; ++nh)
        #pragma unroll
        for (int np = 0; np < 2; ++np)
            bv[nh][np] = bias[(long)bn * 256 + nh * 128 + wn * 32 + np * 16 + cl];

    if (OUT_BF16) {
        unsigned short* epi = lds;
        #pragma unroll
        for (int h = 0; h < 2; ++h) {
            if (h) { LGKM0(); BAR(); }
            #pragma unroll
            for (int mp = 0; mp < MP; ++mp)
                #pragma unroll
                for (int nh = 0; nh < 2; ++nh)
                    #pragma unroll
                    for (int np = 0; np < 2; ++np)
                        #pragma unroll
                        for (int r = 0; r < 4; ++r) {
                            float v = acc[h][nh][mp][np][r] + bv[nh][np];
                            if (RELU) v = fmaxf(v, 0.f);
                            int lrow = wm * (MP * 16) + mp * 16 + r4 + r;
                            int lcol = nh * 128 + wn * 32 + np * 16 + cl;
                            epi[lrow * 264 + lcol] = f2bf(v);
                        }
            LGKM0();
            BAR();
            long rowg0 = (long)bm * (MP * 64) + h * (MP * 32);
            #pragma unroll
            for (int i = 0; i < 2 * MP; ++i) {
                int row = (tid >> 5) + i * 16;
                int cc  = (tid & 31) * 8;
                bf16x8 v8 = *(const bf16x8*)&epi[row * 264 + cc];
                *(bf16x8*)((unsigned short*)Cout + (rowg0 + row) * (long)N + (long)bn * 256 + cc) = v8;
            }
        }
    } else {
        #pragma unroll
        for (int mh = 0; mh < 2; ++mh)
            #pragma unroll
            for (int mp = 0; mp < MP; ++mp) {
                long grow = (long)bm * (MP * 64) + mh * (MP * 32) + wm * (MP * 16) + mp * 16 + r4;
                #pragma unroll
                for (int nh = 0; nh < 2; ++nh)
                    #pragma unroll
                    for (int np = 0; np < 2; ++np) {
                        long gcol = (long)bn * 256 + nh * 128 + wn * 32 + np * 16 + cl;
                        #pragma unroll
                        for (int r = 0; r < 4; ++r) {
                            float v = acc[mh][nh][mp][np][r] + bv[nh][np];
                            if (RELU) v = fmaxf(v, 0.f);
                            ((float*)Cout)[(grow + r) * (long)N + gcol] = v;
                        }
                    }
            }
    }
#undef GLA_
#undef GLB_
#undef READA_
#undef READB_
#undef QUAD
#undef VMW
#undef KTILE
}

// ---------- fused: latent(16) -> quantum circuit -> D1 ----------
__global__ __launch_bounds__(256) void latq_d1(
    const unsigned short* __restrict__ h2,  // B x 1024 bf16
    const float* __restrict__ We3,          // 256 x 1024 (rows 0..15 used)
    const float* __restrict__ be3,          // 256
    const float* __restrict__ P,            // 2 x 16 x 3
    const float* __restrict__ Wd1,          // 1024 x 16
    const float* __restrict__ bd1,          // 1024
    unsigned short* __restrict__ h3)        // B x 1024 bf16
{
    __shared__ float zsh[4][16];
    const int lane = threadIdx.x & 63;
    const int wv   = threadIdx.x >> 6;
    const long row = (long)blockIdx.x * 4 + wv;

    float hreg[16];
    const unsigned short* hr = h2 + row * 1024;
    #pragma unroll
    for (int j = 0; j < 16; ++j) hreg[j] = bf2f(hr[lane + 64 * j]);

    float myth = 0.f;
    #pragma unroll
    for (int q = 0; q < 16; ++q) {
        const float* wq = We3 + q * 1024;
        float p = 0.f;
        #pragma unroll
        for (int j = 0; j < 16; ++j) p += hreg[j] * wq[lane + 64 * j];
        #pragma unroll
        for (int o = 32; o; o >>= 1) p += __shfl_xor(p, o, 64);
        if (lane == q) myth = p + be3[q];
    }

    if (lane < 16) {
        const int q = lane;
        float ar = cosf(0.5f * myth), ai = 0.f;
        float br = sinf(0.5f * myth), bi = 0.f;
        #pragma unroll
        for (int l = 0; l < 2; ++l) {
            const float* pp = P + (l * 16 + q) * 3;
            float t, c, s, ar2, ai2, br2, bi2;
            t = 0.5f * pp[0]; c = cosf(t); s = sinf(t);
            ar2 = c * ar + s * bi;  ai2 = c * ai - s * br;
            br2 = c * br + s * ai;  bi2 = c * bi - s * ar;
            ar = ar2; ai = ai2; br = br2; bi = bi2;
            t = 0.5f * pp[1]; c = cosf(t); s = sinf(t);
            ar2 = c * ar - s * br;  ai2 = c * ai - s * bi;
            br2 = s * ar + c * br;  bi2 = s * ai + c * bi;
            ar = ar2; ai = ai2; br = br2; bi = bi2;
            t = 0.5f * pp[2]; c = cosf(t); s = sinf(t);
            ar2 = ar * c + ai * s;  ai2 = ai * c - ar * s;
            br2 = br * c - bi * s;  bi2 = bi * c + br * s;
            ar = ar2; ai = ai2; br = br2; bi = bi2;
        }
        zsh[wv][q] = ar * ar + ai * ai - (br * br + bi * bi);
    }
    __syncthreads();

    float z[16];
    #pragma unroll
    for (int q = 0; q < 16; ++q) z[q] = zsh[wv][q];

    unsigned short* orow = h3 + row * 1024;
    #pragma unroll
    for (int i = 0; i < 16; ++i) {
        int j = lane + 64 * i;
        const float4* wrow = (const float4*)(Wd1 + j * 16);
        float acc = bd1[j];
        #pragma unroll
        for (int qq = 0; qq < 4; ++qq) {
            float4 w4 = wrow[qq];
            acc += z[qq * 4 + 0] * w4.x + z[qq * 4 + 1] * w4.y
                 + z[qq * 4 + 2] * w4.z + z[qq * 4 + 3] * w4.w;
        }
        orow[j] = f2bf(fmaxf(acc, 0.f));
    }
}

// ---------- host ----------
extern "C" void kernel_launch(void* const* d_in, const int* in_sizes, int n_in,
                              void* d_out, int out_size, void* d_ws, size_t ws_size,
                              hipStream_t stream) {
    const float* x   = (const float*)d_in[0];
    const float* We1 = (const float*)d_in[1];
    const float* be1 = (const float*)d_in[2];
    const float* We2 = (const float*)d_in[3];
    const float* be2 = (const float*)d_in[4];
    const float* We3 = (const float*)d_in[5];
    const float* be3 = (const float*)d_in[6];
    const float* P   = (const float*)d_in[7];
    const float* Wd1 = (const float*)d_in[8];
    const float* bd1 = (const float*)d_in[9];
    const float* Wd2 = (const float*)d_in[10];
    const float* bd2 = (const float*)d_in[11];
    const float* Wd3 = (const float*)d_in[12];
    const float* bd3 = (const float*)d_in[13];

    const int B = 8192, DIN = 4096, NH1 = 2048, NH2 = 1024;

    char* w = (char*)d_ws;
    unsigned short* x_bf   = (unsigned short*)(w);                    // 64MB
    unsigned short* h4     = x_bf;                                    // alias (x dead after G1)
    unsigned short* We1_bf = (unsigned short*)(w + 67108864L);        // 16MB
    unsigned short* We2_bf = (unsigned short*)(w + 83886080L);        // 4MB
    unsigned short* Wd2_bf = (unsigned short*)(w + 88080384L);        // 4MB
    unsigned short* Wd3_bf = (unsigned short*)(w + 92274688L);        // 16MB
    unsigned short* h1     = (unsigned short*)(w + 109051904L);       // 32MB
    unsigned short* h3     = h1;                                      // alias (h1 dead after G2)
    unsigned short* h2     = (unsigned short*)(w + 142606336L);       // 16MB

    Cast5 ca;
    ca.s0 = x;   ca.d0 = x_bf;   ca.n0 = (int)((long)B * DIN / 4);
    ca.s1 = We1; ca.d1 = We1_bf; ca.n1 = (int)((long)NH1 * DIN / 4);
    ca.s2 = We2; ca.d2 = We2_bf; ca.n2 = (int)((long)NH2 * NH1 / 4);
    ca.s3 = Wd2; ca.d3 = Wd2_bf; ca.n3 = (int)((long)NH1 * NH2 / 4);
    ca.s4 = Wd3; ca.d4 = Wd3_bf;
    ca.total = ca.n0 + ca.n1 + ca.n2 + ca.n3 + (int)((long)DIN * NH1 / 4);
    castall<<<2048, 256, 0, stream>>>(ca);

    // G1: h1 = relu(x @ We1^T + be1)   8192x2048 K=4096   (256x256)
    gemm8p<1, 1, 4><<<dim3(NH1 / 256, B / 256), 512, 0, stream>>>(x_bf, We1_bf, be1, h1, NH1, DIN, DIN >> 6);
    // G2: h2 = relu(h1 @ We2^T + be2)  8192x1024 K=2048   (128x256)
    gemm8p<1, 1, 2><<<dim3(NH2 / 256, B / 128), 512, 0, stream>>>(h1, We2_bf, be2, h2, NH2, NH1, NH1 >> 6);
    // latent -> quantum -> D1
    latq_d1<<<dim3(B / 4), 256, 0, stream>>>(h2, We3, be3, P, Wd1, bd1, h3);
    // D2: h4 = relu(h3 @ Wd2^T + bd2)  8192x2048 K=1024   (256x256)
    gemm8p<1, 1, 4><<<dim3(NH1 / 256, B / 256), 512, 0, stream>>>(h3, Wd2_bf, bd2, h4, NH1, NH2, NH2 >> 6);
    // D3: out = h4 @ Wd3^T + bd3       8192x4096 K=2048 -> f32
    gemm8p<0, 0, 4><<<dim3(DIN / 256, B / 256), 512, 0, stream>>>(h4, Wd3_bf, bd3, d_out, DIN, NH1, NH1 >> 6);
}